// Round 1
// baseline (627.143 us; speedup 1.0000x reference)
//
#include <hip/hip_runtime.h>
#include <cstdint>
#include <cstddef>

#define B_ 2
#define S_ 2049
#define E_ 512
#define H_ 8
#define D_ 64
#define WIN_ 1024
#define NT_ 33            // ceil(S/64)
#define MROWS (B_*S_)     // 4098

// ---------------------------------------------------------------------------
// Generic C[M,512] = A[M,512] @ W[512,512] + bias, fp32, 64x64 tile, 4x4 micro
// ---------------------------------------------------------------------------
__global__ __launch_bounds__(256) void gemm_bias_kernel(
    const float* __restrict__ A, const float* __restrict__ W,
    const float* __restrict__ bias, float* __restrict__ C, int M)
{
  const int N = 512, K = 512;
  __shared__ float As[16][68];   // [k][m]
  __shared__ float Bs[16][68];   // [k][n]
  int tid = threadIdx.x;
  int tx = tid & 15, ty = tid >> 4;
  int bm = blockIdx.x * 64, bn = blockIdx.y * 64;
  float acc[4][4] = {};

  for (int k0 = 0; k0 < K; k0 += 16) {
    // A tile: 64 rows x 16 k; each thread loads 4 consecutive k, stores transposed
    {
      int m  = tid >> 2;
      int kq = (tid & 3) << 2;
      int row = bm + m;
      float4 a = make_float4(0.f, 0.f, 0.f, 0.f);
      if (row < M) a = *(const float4*)&A[(size_t)row * K + k0 + kq];
      As[kq + 0][m] = a.x; As[kq + 1][m] = a.y;
      As[kq + 2][m] = a.z; As[kq + 3][m] = a.w;
    }
    // W tile: 16 k x 64 n, direct
    {
      int kb = tid >> 4;
      int nb = (tid & 15) << 2;
      *(float4*)&Bs[kb][nb] = *(const float4*)&W[(size_t)(k0 + kb) * N + bn + nb];
    }
    __syncthreads();
#pragma unroll
    for (int k = 0; k < 16; ++k) {
      float4 av = *(const float4*)&As[k][ty << 2];
      float4 bv = *(const float4*)&Bs[k][tx << 2];
      float aa[4] = {av.x, av.y, av.z, av.w};
      float bb[4] = {bv.x, bv.y, bv.z, bv.w};
#pragma unroll
      for (int i = 0; i < 4; ++i)
#pragma unroll
        for (int j = 0; j < 4; ++j) acc[i][j] += aa[i] * bb[j];
    }
    __syncthreads();
  }

  float4 b4 = *(const float4*)&bias[bn + (tx << 2)];
  float bb[4] = {b4.x, b4.y, b4.z, b4.w};
#pragma unroll
  for (int i = 0; i < 4; ++i) {
    int row = bm + (ty << 2) + i;
    if (row < M) {
      float4 o;
      o.x = acc[i][0] + bb[0]; o.y = acc[i][1] + bb[1];
      o.z = acc[i][2] + bb[2]; o.w = acc[i][3] + bb[3];
      *(float4*)&C[(size_t)row * 512 + bn + (tx << 2)] = o;
    }
  }
}

// ---------------------------------------------------------------------------
// gq[row] = q_flat[row,:] . w_gate[0:E]; gk[row] = k_flat[row,:] . w_gate[E:2E]
// ---------------------------------------------------------------------------
__global__ __launch_bounds__(64) void gate_kernel(
    const float* __restrict__ qf, const float* __restrict__ kf,
    const float* __restrict__ wg, float* __restrict__ gq, float* __restrict__ gk)
{
  int row  = blockIdx.x;
  int lane = threadIdx.x;
  const float* q = qf + (size_t)row * E_;
  const float* k = kf + (size_t)row * E_;
  float sq = 0.f, sk = 0.f;
#pragma unroll
  for (int c = 0; c < E_; c += 64) {
    sq += q[c + lane] * wg[c + lane];
    sk += k[c + lane] * wg[E_ + c + lane];
  }
#pragma unroll
  for (int off = 32; off > 0; off >>= 1) {
    sq += __shfl_down(sq, off);
    sk += __shfl_down(sk, off);
  }
  if (lane == 0) { gq[row] = sq; gk[row] = sk; }
}

// ---------------------------------------------------------------------------
// Flash-style windowed gated attention. One block = (b, h, 64-row q-tile).
// Online softmax per row via 16-lane shuffles; P goes through KPs LDS buffer.
// ---------------------------------------------------------------------------
__global__ __launch_bounds__(256) void attn_kernel(
    const float* __restrict__ qf, const float* __restrict__ kf,
    const float* __restrict__ vf, const float* __restrict__ gq,
    const float* __restrict__ gk, const float* __restrict__ bgate,
    float* __restrict__ aout)
{
  __shared__ float Qs[64][68];    // [d][m]
  __shared__ float KPs[64][68];   // phase 1: K^T [d][n]; phase 2: P^T [n][m]
  __shared__ float Vs[64][68];    // [n][d]
  __shared__ float gqs[64];
  __shared__ float gks[64];

  int tid = threadIdx.x;
  int tx = tid & 15, ty = tid >> 4;
  int qt = blockIdx.x % NT_;
  int h  = (blockIdx.x / NT_) % H_;
  int b  = blockIdx.x / (NT_ * H_);
  int i0 = qt * 64;
  float bg = bgate[0];
  const float scale = 0.125f;                       // D^-0.5
  const float bias_coef = -0.5f / (512.f * 512.f);  // sigma = WIN/2 = 512

  // stage Q tile transposed: Qs[d][m]
#pragma unroll
  for (int r = 0; r < 4; ++r) {
    int vi = tid + r * 256;
    int m  = vi >> 4;
    int dq = (vi & 15) << 2;
    int ig = i0 + m;
    float4 v = make_float4(0.f, 0.f, 0.f, 0.f);
    if (ig < S_) v = *(const float4*)&qf[((size_t)b * S_ + ig) * E_ + h * 64 + dq];
    Qs[dq + 0][m] = v.x; Qs[dq + 1][m] = v.y;
    Qs[dq + 2][m] = v.z; Qs[dq + 3][m] = v.w;
  }
  if (tid < 64) {
    int ig = i0 + tid;
    gqs[tid] = (ig < S_) ? gq[b * S_ + ig] : 0.f;
  }

  float Oacc[4][4] = {};
  float m_run[4] = {-1e30f, -1e30f, -1e30f, -1e30f};
  float l_run[4] = {0.f, 0.f, 0.f, 0.f};

  int jt_lo = (i0 - WIN_) > 0 ? (i0 - WIN_) >> 6 : 0;
  int hi_j  = i0 + 63 + WIN_; if (hi_j > S_ - 1) hi_j = S_ - 1;
  int jt_hi = hi_j >> 6;

  for (int jt = jt_lo; jt <= jt_hi; ++jt) {
    int j0 = jt * 64;
    __syncthreads();  // prior iteration done with KPs/Vs (and Q staging on iter 1)

    // stage K (transposed) and V tiles
#pragma unroll
    for (int r = 0; r < 4; ++r) {
      int vi = tid + r * 256;
      int n  = vi >> 4;
      int dq = (vi & 15) << 2;
      int jg = j0 + n;
      float4 kv = make_float4(0.f, 0.f, 0.f, 0.f);
      float4 vv = make_float4(0.f, 0.f, 0.f, 0.f);
      if (jg < S_) {
        kv = *(const float4*)&kf[((size_t)b * S_ + jg) * E_ + h * 64 + dq];
        vv = *(const float4*)&vf[((size_t)b * S_ + jg) * E_ + h * 64 + dq];
      }
      KPs[dq + 0][n] = kv.x; KPs[dq + 1][n] = kv.y;
      KPs[dq + 2][n] = kv.z; KPs[dq + 3][n] = kv.w;
      *(float4*)&Vs[n][dq] = vv;
    }
    if (tid < 64) {
      int jg = j0 + tid;
      gks[tid] = (jg < S_) ? gk[b * S_ + jg] : 0.f;
    }
    __syncthreads();

    // scores: s[i][j] = sum_d Q[row][d] * K[col][d]
    float s[4][4] = {};
#pragma unroll 8
    for (int d = 0; d < 64; ++d) {
      float4 qa = *(const float4*)&Qs[d][ty << 2];
      float4 kb = *(const float4*)&KPs[d][tx << 2];
      float qv[4] = {qa.x, qa.y, qa.z, qa.w};
      float kv2[4] = {kb.x, kb.y, kb.z, kb.w};
#pragma unroll
      for (int i = 0; i < 4; ++i)
#pragma unroll
        for (int j = 0; j < 4; ++j) s[i][j] += qv[i] * kv2[j];
    }

    // bias + gate + band mask
    float val[4][4];
#pragma unroll
    for (int i = 0; i < 4; ++i) {
      int ig = i0 + (ty << 2) + i;
      float gqv = gqs[(ty << 2) + i];
#pragma unroll
      for (int j = 0; j < 4; ++j) {
        int jg = j0 + (tx << 2) + j;
        int dist = ig - jg; if (dist < 0) dist = -dist;
        if (ig < S_ && jg < S_ && dist <= WIN_) {
          float bias = bias_coef * (float)(dist * dist);
          float g = gqv + gks[(tx << 2) + j] + bg;
          float gate = 1.f / (1.f + __expf(-g));
          val[i][j] = (s[i][j] * scale + bias) * gate;
        } else {
          val[i][j] = -1e30f;
        }
      }
    }

    __syncthreads();  // all threads done reading KPs as K; reuse it for P^T

    // online softmax: each row r=ty*4+i is owned by 16 consecutive lanes
#pragma unroll
    for (int i = 0; i < 4; ++i) {
      float vmax = fmaxf(fmaxf(val[i][0], val[i][1]), fmaxf(val[i][2], val[i][3]));
#pragma unroll
      for (int off = 1; off < 16; off <<= 1)
        vmax = fmaxf(vmax, __shfl_xor(vmax, off, 16));
      float mn = fmaxf(m_run[i], vmax);
      float al = __expf(m_run[i] - mn);  // -1e30-case: underflows to 0 or exp(0)=1, both correct
      float p[4];
      float psum = 0.f;
#pragma unroll
      for (int j = 0; j < 4; ++j) {
        p[j] = (val[i][j] < -1e29f) ? 0.f : __expf(val[i][j] - mn);
        psum += p[j];
      }
#pragma unroll
      for (int off = 1; off < 16; off <<= 1)
        psum += __shfl_xor(psum, off, 16);
      l_run[i] = l_run[i] * al + psum;
      m_run[i] = mn;
#pragma unroll
      for (int j = 0; j < 4; ++j) {
        Oacc[i][j] *= al;
        KPs[(tx << 2) + j][(ty << 2) + i] = p[j];  // P^T: [n][m]
      }
    }
    __syncthreads();

    // O[row][d] += sum_jj P[row][jj] * V[jj][d]
#pragma unroll 8
    for (int jj = 0; jj < 64; ++jj) {
      float4 pv = *(const float4*)&KPs[jj][ty << 2];
      float4 vv = *(const float4*)&Vs[jj][tx << 2];
      float pr[4] = {pv.x, pv.y, pv.z, pv.w};
      float vr[4] = {vv.x, vv.y, vv.z, vv.w};
#pragma unroll
      for (int i = 0; i < 4; ++i)
#pragma unroll
        for (int j = 0; j < 4; ++j) Oacc[i][j] += pr[i] * vr[j];
    }
  }

  // normalize + store: aout[b][i][h*64 + d]
#pragma unroll
  for (int i = 0; i < 4; ++i) {
    int ig = i0 + (ty << 2) + i;
    if (ig < S_) {
      float inv = 1.f / l_run[i];
      float4 o;
      o.x = Oacc[i][0] * inv; o.y = Oacc[i][1] * inv;
      o.z = Oacc[i][2] * inv; o.w = Oacc[i][3] * inv;
      *(float4*)&aout[((size_t)b * S_ + ig) * E_ + h * 64 + (tx << 2)] = o;
    }
  }
}

// ---------------------------------------------------------------------------
extern "C" void kernel_launch(void* const* d_in, const int* in_sizes, int n_in,
                              void* d_out, int out_size, void* d_ws, size_t ws_size,
                              hipStream_t stream) {
  const float* x  = (const float*)d_in[0];
  const float* Wq = (const float*)d_in[1];
  const float* bq = (const float*)d_in[2];
  const float* Wk = (const float*)d_in[3];
  const float* bk = (const float*)d_in[4];
  const float* Wv = (const float*)d_in[5];
  const float* bv = (const float*)d_in[6];
  const float* Wo = (const float*)d_in[7];
  const float* bo = (const float*)d_in[8];
  const float* wg = (const float*)d_in[9];
  const float* bg = (const float*)d_in[10];

  float* ws = (float*)d_ws;
  size_t nBSE = (size_t)MROWS * E_;  // 2,098,176 floats
  float* qf   = ws;
  float* kf   = qf + nBSE;
  float* vf   = kf + nBSE;
  float* gq   = vf + nBSE;
  float* gk   = gq + MROWS;
  float* aout = gk + MROWS;          // total ws use: 4*nBSE + 2*MROWS floats ≈ 33.6 MB

  dim3 blk(256);
  dim3 gemm_grid(65, 8);             // ceil(4098/64) x 512/64

  hipLaunchKernelGGL(gemm_bias_kernel, gemm_grid, blk, 0, stream, x, Wq, bq, qf, MROWS);
  hipLaunchKernelGGL(gemm_bias_kernel, gemm_grid, blk, 0, stream, x, Wk, bk, kf, MROWS);
  hipLaunchKernelGGL(gemm_bias_kernel, gemm_grid, blk, 0, stream, x, Wv, bv, vf, MROWS);
  hipLaunchKernelGGL(gate_kernel, dim3(MROWS), dim3(64), 0, stream, qf, kf, wg, gq, gk);
  hipLaunchKernelGGL(attn_kernel, dim3(B_ * H_ * NT_), blk, 0, stream,
                     qf, kf, vf, gq, gk, bg, aout);
  hipLaunchKernelGGL(gemm_bias_kernel, gemm_grid, blk, 0, stream, aout, Wo, bo,
                     (float*)d_out, MROWS);
}

// Round 2
// 234.639 us; speedup vs baseline: 2.6728x; 2.6728x over previous
//
#include <hip/hip_runtime.h>
#include <cstdint>
#include <cstddef>

#define B_ 2
#define S_ 2049
#define E_ 512
#define H_ 8
#define WIN_ 1024
#define NT_ 33            // ceil(S/64)
#define MROWS (B_*S_)     // 4098

typedef unsigned short ushort_t;
typedef __attribute__((ext_vector_type(8))) short bf16x8;   // 8 bf16 (4 VGPRs)
typedef __attribute__((ext_vector_type(4))) float f32x4;

#define MFMA16(a,b,c) __builtin_amdgcn_mfma_f32_16x16x32_bf16(a,b,c,0,0,0)

__device__ __forceinline__ ushort_t f2bf(float f) {          // RNE fp32->bf16
  unsigned int u = __float_as_uint(f);
  u += 0x7fffu + ((u >> 16) & 1u);
  return (ushort_t)(u >> 16);
}
__device__ __forceinline__ float bf2f(ushort_t h) {
  return __uint_as_float(((unsigned int)h) << 16);
}

// ---------------------------------------------------------------------------
// x fp32 -> bf16 (exact grid: 2049*256 float4s)
// ---------------------------------------------------------------------------
__global__ __launch_bounds__(256) void convert_x_kernel(
    const float* __restrict__ x, ushort_t* __restrict__ xb)
{
  int idx = blockIdx.x * 256 + threadIdx.x;
  float4 v = ((const float4*)x)[idx];
  ushort4 o;
  o.x = f2bf(v.x); o.y = f2bf(v.y); o.z = f2bf(v.z); o.w = f2bf(v.w);
  ((ushort4*)xb)[idx] = o;
}

// ---------------------------------------------------------------------------
// W [k][n] fp32 -> Wt [n][k] bf16; z=3 (Wo) emits hi+lo split
// ---------------------------------------------------------------------------
__global__ __launch_bounds__(256) void convert_w_kernel(
    const float* __restrict__ W0, const float* __restrict__ W1,
    const float* __restrict__ W2, const float* __restrict__ W3,
    ushort_t* __restrict__ Wt_all, ushort_t* __restrict__ WoHi,
    ushort_t* __restrict__ WoLo)
{
  __shared__ float tile[32][33];
  int z = blockIdx.z;
  const float* W = (z == 0) ? W0 : (z == 1) ? W1 : (z == 2) ? W2 : W3;
  int k0 = blockIdx.x * 32, n0 = blockIdx.y * 32;
  int r = threadIdx.x >> 5, c = threadIdx.x & 31;
#pragma unroll
  for (int i = 0; i < 4; ++i) {
    int rr = r + i * 8;
    tile[rr][c] = W[(size_t)(k0 + rr) * E_ + n0 + c];
  }
  __syncthreads();
#pragma unroll
  for (int i = 0; i < 4; ++i) {
    int rr = r + i * 8;
    float v = tile[c][rr];                       // = W[k0+c][n0+rr]
    size_t dst = (size_t)(n0 + rr) * E_ + k0 + c;
    if (z < 3) {
      Wt_all[(size_t)z * E_ * E_ + dst] = f2bf(v);
    } else {
      ushort_t hi = f2bf(v);
      WoHi[dst] = hi;
      WoLo[dst] = f2bf(v - bf2f(hi));
    }
  }
}

// ---------------------------------------------------------------------------
// QKV projection: C_z = bf16(xb @ W_z + b_z), z = blockIdx.z in {q,k,v}
// 64x64 tile, 4 waves x (16m x 64n), 16x16x32 bf16 MFMA
// ---------------------------------------------------------------------------
__global__ __launch_bounds__(256) void gemm_qkv_kernel(
    const ushort_t* __restrict__ xb, const ushort_t* __restrict__ Wt_all,
    const float* __restrict__ bq, const float* __restrict__ bk,
    const float* __restrict__ bv, ushort_t* __restrict__ qkvb)
{
  __shared__ __align__(16) ushort_t As[64][40];
  __shared__ __align__(16) ushort_t Bs[64][40];
  int tid = threadIdx.x;
  int lane = tid & 63, w = tid >> 6;
  int l15 = lane & 15, quad = lane >> 4;
  int z = blockIdx.z;
  const ushort_t* Wt = Wt_all + (size_t)z * E_ * E_;
  const float* bias = (z == 0) ? bq : (z == 1) ? bk : bv;
  ushort_t* C = qkvb + (size_t)z * MROWS * E_;
  int bm = blockIdx.x * 64, bn = blockIdx.y * 64;

  int srow = tid >> 2, skq = (tid & 3) * 8;
  int arow = bm + srow; if (arow >= MROWS) arow = MROWS - 1;

  const f32x4 fz = {0.f, 0.f, 0.f, 0.f};
  f32x4 acc[4] = {fz, fz, fz, fz};

  for (int k0 = 0; k0 < E_; k0 += 32) {
    __syncthreads();
    *(int4*)&As[srow][skq] = *(const int4*)&xb[(size_t)arow * E_ + k0 + skq];
    *(int4*)&Bs[srow][skq] = *(const int4*)&Wt[(size_t)(bn + srow) * E_ + k0 + skq];
    __syncthreads();
    bf16x8 a = *(const bf16x8*)&As[w * 16 + l15][quad * 8];
#pragma unroll
    for (int nt = 0; nt < 4; ++nt) {
      bf16x8 bfr = *(const bf16x8*)&Bs[nt * 16 + l15][quad * 8];
      acc[nt] = MFMA16(a, bfr, acc[nt]);
    }
  }
#pragma unroll
  for (int nt = 0; nt < 4; ++nt) {
    float bb = bias[bn + nt * 16 + l15];
#pragma unroll
    for (int r = 0; r < 4; ++r) {
      int m = bm + w * 16 + quad * 4 + r;
      if (m < MROWS)
        C[(size_t)m * E_ + bn + nt * 16 + l15] = f2bf(acc[nt][r] + bb);
    }
  }
}

// ---------------------------------------------------------------------------
// gq/gk row dots (bf16 inputs)
// ---------------------------------------------------------------------------
__global__ __launch_bounds__(64) void gate_kernel(
    const ushort_t* __restrict__ qb, const ushort_t* __restrict__ kb,
    const float* __restrict__ wg, float* __restrict__ gq, float* __restrict__ gk)
{
  int row = blockIdx.x, lane = threadIdx.x;
  const ushort_t* q = qb + (size_t)row * E_;
  const ushort_t* k = kb + (size_t)row * E_;
  float sq = 0.f, sk = 0.f;
#pragma unroll
  for (int c = 0; c < E_; c += 64) {
    sq += bf2f(q[c + lane]) * wg[c + lane];
    sk += bf2f(k[c + lane]) * wg[E_ + c + lane];
  }
#pragma unroll
  for (int o = 32; o > 0; o >>= 1) { sq += __shfl_down(sq, o); sk += __shfl_down(sk, o); }
  if (lane == 0) { gq[row] = sq; gk[row] = sk; }
}

// ---------------------------------------------------------------------------
// MFMA flash attention: block = (qt,h,b); 4 waves x 16 q-rows; 64-col k-tiles.
// K,V^T staged in LDS; softmax on C-frags via 16-lane shuffles; P via per-wave
// LDS round-trip (no cross-wave barrier). Output = hi/lo bf16 split.
// ---------------------------------------------------------------------------
__global__ __launch_bounds__(256) void attn_kernel(
    const ushort_t* __restrict__ qb, const ushort_t* __restrict__ kb,
    const ushort_t* __restrict__ vb, const float* __restrict__ gq,
    const float* __restrict__ gk, const float* __restrict__ bgate,
    ushort_t* __restrict__ ahi, ushort_t* __restrict__ alo)
{
  __shared__ __align__(16) ushort_t Ks[64][72];
  __shared__ __align__(16) ushort_t Vt[64][72];
  __shared__ __align__(16) ushort_t Ps[4][16][72];

  int tid = threadIdx.x;
  int lane = tid & 63, w = tid >> 6;
  int l15 = lane & 15, quad = lane >> 4;

  // heavy q-tiles (middle of sequence) dispatch first for tail balance
  int bh = blockIdx.x & 15;
  int qidx = blockIdx.x >> 4;
  int offq = (qidx + 1) >> 1;
  int qt = 16 + ((qidx & 1) ? offq : -offq);
  int h = bh & 7, b = bh >> 3;
  int i0 = qt * 64;
  float bg = bgate[0];
  const float scale = 0.125f;
  const float bias_coef = -0.5f / (512.f * 512.f);   // sigma = WIN/2

  // Q A-fragments (held in registers across the whole k-loop)
  int iq = i0 + w * 16 + l15;
  int iqc = iq < S_ ? iq : S_ - 1;
  bf16x8 qf0 = *(const bf16x8*)&qb[((size_t)(b * S_ + iqc)) * E_ + h * 64 + quad * 8];
  bf16x8 qf1 = *(const bf16x8*)&qb[((size_t)(b * S_ + iqc)) * E_ + h * 64 + 32 + quad * 8];

  int iv[4]; float gqv[4]; bool rv[4];
#pragma unroll
  for (int r = 0; r < 4; ++r) {
    int i = i0 + w * 16 + quad * 4 + r;      // C-frag row for this reg
    iv[r] = i; rv[r] = (i < S_);
    gqv[r] = gq[b * S_ + (i < S_ ? i : S_ - 1)];
  }

  const f32x4 fz = {0.f, 0.f, 0.f, 0.f};
  f32x4 Ov[4] = {fz, fz, fz, fz};
  float m_run[4] = {-1e30f, -1e30f, -1e30f, -1e30f};
  float l_run[4] = {0.f, 0.f, 0.f, 0.f};

  int jt_lo = (i0 - WIN_) >> 6; if (jt_lo < 0) jt_lo = 0;
  int jt_hi = (i0 + 63 + WIN_) >> 6; if (jt_hi > NT_ - 1) jt_hi = NT_ - 1;

  int sj = tid >> 2, sdq = (tid & 3) * 16;   // staging map: 16 j x 4 d-chunks

  for (int jt = jt_lo; jt <= jt_hi; ++jt) {
    int j0 = jt * 64;
    __syncthreads();
    {
      int jg = j0 + sj; int jc = jg < S_ ? jg : S_ - 1;
      const ushort_t* ksrc = kb + ((size_t)(b * S_ + jc)) * E_ + h * 64 + sdq;
      *(int4*)&Ks[sj][sdq]     = *(const int4*)ksrc;       // K row-major
      *(int4*)&Ks[sj][sdq + 8] = *(const int4*)(ksrc + 8);
      const ushort_t* vsrc = vb + ((size_t)(b * S_ + jc)) * E_ + h * 64 + sdq;
      union { int4 v4[2]; ushort_t us[16]; } vv;
      vv.v4[0] = *(const int4*)vsrc;
      vv.v4[1] = *(const int4*)(vsrc + 8);
#pragma unroll
      for (int e = 0; e < 16; ++e) Vt[sdq + e][sj] = vv.us[e];  // V transposed
    }
    __syncthreads();

    float gkv[4]; int jv[4];
#pragma unroll
    for (int nt = 0; nt < 4; ++nt) {
      int j = j0 + nt * 16 + l15;
      jv[nt] = j;
      gkv[nt] = gk[b * S_ + (j < S_ ? j : S_ - 1)];
    }

    // S = Q @ K^T  (C layout: row = quad*4+reg, col = l15 within nt*16)
    f32x4 sf[4];
#pragma unroll
    for (int nt = 0; nt < 4; ++nt) {
      bf16x8 k0 = *(const bf16x8*)&Ks[nt * 16 + l15][quad * 8];
      bf16x8 k1 = *(const bf16x8*)&Ks[nt * 16 + l15][32 + quad * 8];
      f32x4 s = fz;
      s = MFMA16(qf0, k0, s);
      s = MFMA16(qf1, k1, s);
      sf[nt] = s;
    }

    // bias + gate + band mask
    float val[4][4];
#pragma unroll
    for (int nt = 0; nt < 4; ++nt) {
#pragma unroll
      for (int r = 0; r < 4; ++r) {
        int dist = iv[r] - jv[nt]; dist = dist < 0 ? -dist : dist;
        bool ok = rv[r] && (jv[nt] < S_) && (dist <= WIN_);
        float dd = (float)dist;
        float g = gqv[r] + gkv[nt] + bg;
        float gate = __builtin_amdgcn_rcpf(1.f + __expf(-g));
        float t = (sf[nt][r] * scale + bias_coef * dd * dd) * gate;
        val[nt][r] = ok ? t : -1e30f;
      }
    }

    // online softmax per row r (16 lanes of each quad hold one row)
    float al[4];
#pragma unroll
    for (int r = 0; r < 4; ++r) {
      float vm = fmaxf(fmaxf(val[0][r], val[1][r]), fmaxf(val[2][r], val[3][r]));
#pragma unroll
      for (int o = 1; o < 16; o <<= 1) vm = fmaxf(vm, __shfl_xor(vm, o, 16));
      float mn = fmaxf(m_run[r], vm);
      al[r] = __expf(m_run[r] - mn);
      float psum = 0.f;
#pragma unroll
      for (int nt = 0; nt < 4; ++nt) {
        float p = (val[nt][r] > -1e29f) ? __expf(val[nt][r] - mn) : 0.f;
        val[nt][r] = p;
        psum += p;
      }
#pragma unroll
      for (int o = 1; o < 16; o <<= 1) psum += __shfl_xor(psum, o, 16);
      l_run[r] = l_run[r] * al[r] + psum;
      m_run[r] = mn;
    }

    // P -> per-wave LDS (bf16), rescale O
#pragma unroll
    for (int nt = 0; nt < 4; ++nt) {
#pragma unroll
      for (int r = 0; r < 4; ++r) {
        Ps[w][quad * 4 + r][nt * 16 + l15] = f2bf(val[nt][r]);
        Ov[nt][r] = Ov[nt][r] * al[r];
      }
    }

    // O += P @ V
    bf16x8 p0 = *(const bf16x8*)&Ps[w][l15][quad * 8];
    bf16x8 p1 = *(const bf16x8*)&Ps[w][l15][32 + quad * 8];
#pragma unroll
    for (int nt = 0; nt < 4; ++nt) {
      bf16x8 v0 = *(const bf16x8*)&Vt[nt * 16 + l15][quad * 8];
      bf16x8 v1 = *(const bf16x8*)&Vt[nt * 16 + l15][32 + quad * 8];
      Ov[nt] = MFMA16(p0, v0, Ov[nt]);
      Ov[nt] = MFMA16(p1, v1, Ov[nt]);
    }
  }

  // normalize + split-store (hi/lo bf16, error ~2^-18)
#pragma unroll
  for (int r = 0; r < 4; ++r) {
    if (!rv[r]) continue;
    float inv = 1.f / l_run[r];
#pragma unroll
    for (int nt = 0; nt < 4; ++nt) {
      float o = Ov[nt][r] * inv;
      ushort_t hi = f2bf(o);
      size_t idx = ((size_t)(b * S_ + iv[r])) * E_ + h * 64 + nt * 16 + l15;
      ahi[idx] = hi;
      alo[idx] = f2bf(o - bf2f(hi));
    }
  }
}

// ---------------------------------------------------------------------------
// Output projection: fp32-accurate via split bf16:
// C = Ahi@Whi + Alo@Whi + Ahi@Wlo + bias   (fp32 out)
// ---------------------------------------------------------------------------
__global__ __launch_bounds__(256) void gemm_out_kernel(
    const ushort_t* __restrict__ Ahi, const ushort_t* __restrict__ Alo,
    const ushort_t* __restrict__ Whi, const ushort_t* __restrict__ Wlo,
    const float* __restrict__ bias, float* __restrict__ C)
{
  __shared__ __align__(16) ushort_t AsH[64][40];
  __shared__ __align__(16) ushort_t AsL[64][40];
  __shared__ __align__(16) ushort_t BsH[64][40];
  __shared__ __align__(16) ushort_t BsL[64][40];
  int tid = threadIdx.x;
  int lane = tid & 63, w = tid >> 6;
  int l15 = lane & 15, quad = lane >> 4;
  int bm = blockIdx.x * 64, bn = blockIdx.y * 64;
  int srow = tid >> 2, skq = (tid & 3) * 8;
  int arow = bm + srow; if (arow >= MROWS) arow = MROWS - 1;

  const f32x4 fz = {0.f, 0.f, 0.f, 0.f};
  f32x4 acc[4] = {fz, fz, fz, fz};

  for (int k0 = 0; k0 < E_; k0 += 32) {
    __syncthreads();
    *(int4*)&AsH[srow][skq] = *(const int4*)&Ahi[(size_t)arow * E_ + k0 + skq];
    *(int4*)&AsL[srow][skq] = *(const int4*)&Alo[(size_t)arow * E_ + k0 + skq];
    *(int4*)&BsH[srow][skq] = *(const int4*)&Whi[(size_t)(bn + srow) * E_ + k0 + skq];
    *(int4*)&BsL[srow][skq] = *(const int4*)&Wlo[(size_t)(bn + srow) * E_ + k0 + skq];
    __syncthreads();
    bf16x8 ah = *(const bf16x8*)&AsH[w * 16 + l15][quad * 8];
    bf16x8 alv = *(const bf16x8*)&AsL[w * 16 + l15][quad * 8];
#pragma unroll
    for (int nt = 0; nt < 4; ++nt) {
      bf16x8 bh2 = *(const bf16x8*)&BsH[nt * 16 + l15][quad * 8];
      bf16x8 bl2 = *(const bf16x8*)&BsL[nt * 16 + l15][quad * 8];
      acc[nt] = MFMA16(ah, bh2, acc[nt]);
      acc[nt] = MFMA16(alv, bh2, acc[nt]);
      acc[nt] = MFMA16(ah, bl2, acc[nt]);
    }
  }
#pragma unroll
  for (int nt = 0; nt < 4; ++nt) {
    float bb = bias[bn + nt * 16 + l15];
#pragma unroll
    for (int r = 0; r < 4; ++r) {
      int m = bm + w * 16 + quad * 4 + r;
      if (m < MROWS)
        C[(size_t)m * E_ + bn + nt * 16 + l15] = acc[nt][r] + bb;
    }
  }
}

// ---------------------------------------------------------------------------
extern "C" void kernel_launch(void* const* d_in, const int* in_sizes, int n_in,
                              void* d_out, int out_size, void* d_ws, size_t ws_size,
                              hipStream_t stream) {
  const float* x  = (const float*)d_in[0];
  const float* Wq = (const float*)d_in[1];
  const float* bq = (const float*)d_in[2];
  const float* Wk = (const float*)d_in[3];
  const float* bk = (const float*)d_in[4];
  const float* Wv = (const float*)d_in[5];
  const float* bv = (const float*)d_in[6];
  const float* Wo = (const float*)d_in[7];
  const float* bo = (const float*)d_in[8];
  const float* wg = (const float*)d_in[9];
  const float* bg = (const float*)d_in[10];

  char* p = (char*)d_ws;
  ushort_t* xb     = (ushort_t*)p; p += (size_t)MROWS * E_ * 2;        // 4.2 MB
  ushort_t* Wt_all = (ushort_t*)p; p += (size_t)3 * E_ * E_ * 2;       // 1.5 MB
  ushort_t* WoHi   = (ushort_t*)p; p += (size_t)E_ * E_ * 2;
  ushort_t* WoLo   = (ushort_t*)p; p += (size_t)E_ * E_ * 2;
  ushort_t* qkvb   = (ushort_t*)p; p += (size_t)3 * MROWS * E_ * 2;    // 12.6 MB
  float*    gqv    = (float*)p;    p += (size_t)4104 * 4;
  float*    gkv    = (float*)p;    p += (size_t)4104 * 4;
  ushort_t* aHi    = (ushort_t*)p; p += (size_t)MROWS * E_ * 2;
  ushort_t* aLo    = (ushort_t*)p; p += (size_t)MROWS * E_ * 2;        // total ~27.8MB

  hipLaunchKernelGGL(convert_x_kernel, dim3(2049), dim3(256), 0, stream, x, xb);
  hipLaunchKernelGGL(convert_w_kernel, dim3(16, 16, 4), dim3(256), 0, stream,
                     Wq, Wk, Wv, Wo, Wt_all, WoHi, WoLo);
  hipLaunchKernelGGL(gemm_qkv_kernel, dim3(65, 8, 3), dim3(256), 0, stream,
                     xb, Wt_all, bq, bk, bv, qkvb);
  hipLaunchKernelGGL(gate_kernel, dim3(MROWS), dim3(64), 0, stream,
                     qkvb, qkvb + (size_t)MROWS * E_, wg, gqv, gkv);
  hipLaunchKernelGGL(attn_kernel, dim3(NT_ * 16), dim3(256), 0, stream,
                     qkvb, qkvb + (size_t)MROWS * E_, qkvb + (size_t)2 * MROWS * E_,
                     gqv, gkv, bg, aHi, aLo);
  hipLaunchKernelGGL(gemm_out_kernel, dim3(65, 8), dim3(256), 0, stream,
                     aHi, aLo, WoHi, WoLo, bo, (float*)d_out);
}

// Round 3
// 233.532 us; speedup vs baseline: 2.6855x; 1.0047x over previous
//
#include <hip/hip_runtime.h>
#include <cstdint>
#include <cstddef>

#define B_ 2
#define S_ 2049
#define E_ 512
#define H_ 8
#define WIN_ 1024
#define NT_ 33            // ceil(S/64) k-tiles
#define MROWS (B_*S_)     // 4098
#define SP_ 2112          // padded seq for vT rows (33*64), 16B-aligned

typedef unsigned short ushort_t;
typedef __attribute__((ext_vector_type(8))) short bf16x8;   // 8 bf16 (4 VGPRs)
typedef __attribute__((ext_vector_type(4))) float f32x4;

#define MFMA16(a,b,c) __builtin_amdgcn_mfma_f32_16x16x32_bf16(a,b,c,0,0,0)

__device__ __forceinline__ ushort_t f2bf(float f) {          // RNE fp32->bf16
  unsigned int u = __float_as_uint(f);
  u += 0x7fffu + ((u >> 16) & 1u);
  return (ushort_t)(u >> 16);
}
__device__ __forceinline__ float bf2f(ushort_t h) {
  return __uint_as_float(((unsigned int)h) << 16);
}

// ---------------------------------------------------------------------------
// x fp32 -> bf16 (exact grid: 2049 blocks x 256 float4)
// ---------------------------------------------------------------------------
__global__ __launch_bounds__(256) void convert_x_kernel(
    const float* __restrict__ x, ushort_t* __restrict__ xb)
{
  int idx = blockIdx.x * 256 + threadIdx.x;
  float4 v = ((const float4*)x)[idx];
  ushort4 o;
  o.x = f2bf(v.x); o.y = f2bf(v.y); o.z = f2bf(v.z); o.w = f2bf(v.w);
  ((ushort4*)xb)[idx] = o;
}

// ---------------------------------------------------------------------------
// W [k][n] fp32 -> Wt [n][k] bf16; z=3 (Wo) emits hi+lo split
// ---------------------------------------------------------------------------
__global__ __launch_bounds__(256) void convert_w_kernel(
    const float* __restrict__ W0, const float* __restrict__ W1,
    const float* __restrict__ W2, const float* __restrict__ W3,
    ushort_t* __restrict__ Wt_all, ushort_t* __restrict__ WoHi,
    ushort_t* __restrict__ WoLo)
{
  __shared__ float tile[32][33];
  int z = blockIdx.z;
  const float* W = (z == 0) ? W0 : (z == 1) ? W1 : (z == 2) ? W2 : W3;
  int k0 = blockIdx.x * 32, n0 = blockIdx.y * 32;
  int r = threadIdx.x >> 5, c = threadIdx.x & 31;
#pragma unroll
  for (int i = 0; i < 4; ++i) {
    int rr = r + i * 8;
    tile[rr][c] = W[(size_t)(k0 + rr) * E_ + n0 + c];
  }
  __syncthreads();
#pragma unroll
  for (int i = 0; i < 4; ++i) {
    int rr = r + i * 8;
    float v = tile[c][rr];                       // = W[k0+c][n0+rr]
    size_t dst = (size_t)(n0 + rr) * E_ + k0 + c;
    if (z < 3) {
      Wt_all[(size_t)z * E_ * E_ + dst] = f2bf(v);
    } else {
      ushort_t hi = f2bf(v);
      WoHi[dst] = hi;
      WoLo[dst] = f2bf(v - bf2f(hi));
    }
  }
}

// ---------------------------------------------------------------------------
// QKV projection, 128x64 tile, 4 waves x (32m x 64n), BK=32.
// z<2 (q,k): row-major bf16. z==2 (v): scattered transposed store to
// vT[b][h][d][s] so attention can stage V^T with coalesced loads.
// ---------------------------------------------------------------------------
__global__ __launch_bounds__(256) void gemm_qkv_kernel(
    const ushort_t* __restrict__ xb, const ushort_t* __restrict__ Wt_all,
    const float* __restrict__ bq, const float* __restrict__ bk,
    const float* __restrict__ bv, ushort_t* __restrict__ qkb,
    ushort_t* __restrict__ vT)
{
  __shared__ __align__(16) ushort_t As[128][40];
  __shared__ __align__(16) ushort_t Bs[64][40];
  int tid = threadIdx.x;
  int lane = tid & 63, w = tid >> 6;
  int l15 = lane & 15, quad = lane >> 4;
  int z = blockIdx.z;
  const ushort_t* Wt = Wt_all + (size_t)z * E_ * E_;
  const float* bias = (z == 0) ? bq : (z == 1) ? bk : bv;
  int bm = blockIdx.x * 128, bn = blockIdx.y * 64;

  int ar = tid >> 2, akq = (tid & 3) * 8;
  int am0 = bm + ar;      if (am0 >= MROWS) am0 = MROWS - 1;
  int am1 = bm + ar + 64; if (am1 >= MROWS) am1 = MROWS - 1;

  const f32x4 fz = {0.f, 0.f, 0.f, 0.f};
  f32x4 acc[2][4] = {{fz, fz, fz, fz}, {fz, fz, fz, fz}};

  for (int k0 = 0; k0 < E_; k0 += 32) {
    __syncthreads();
    *(int4*)&As[ar][akq]      = *(const int4*)&xb[(size_t)am0 * E_ + k0 + akq];
    *(int4*)&As[ar + 64][akq] = *(const int4*)&xb[(size_t)am1 * E_ + k0 + akq];
    *(int4*)&Bs[ar][akq]      = *(const int4*)&Wt[(size_t)(bn + ar) * E_ + k0 + akq];
    __syncthreads();
    bf16x8 a0 = *(const bf16x8*)&As[w * 32 + l15][quad * 8];
    bf16x8 a1 = *(const bf16x8*)&As[w * 32 + 16 + l15][quad * 8];
#pragma unroll
    for (int nt = 0; nt < 4; ++nt) {
      bf16x8 bfr = *(const bf16x8*)&Bs[nt * 16 + l15][quad * 8];
      acc[0][nt] = MFMA16(a0, bfr, acc[0][nt]);
      acc[1][nt] = MFMA16(a1, bfr, acc[1][nt]);
    }
  }

  if (z < 2) {
    ushort_t* C = qkb + (size_t)z * MROWS * E_;
#pragma unroll
    for (int c = 0; c < 2; ++c)
#pragma unroll
      for (int nt = 0; nt < 4; ++nt) {
        float bb = bias[bn + nt * 16 + l15];
#pragma unroll
        for (int r = 0; r < 4; ++r) {
          int m = bm + w * 32 + c * 16 + quad * 4 + r;
          if (m < MROWS)
            C[(size_t)m * E_ + bn + nt * 16 + l15] = f2bf(acc[c][nt][r] + bb);
        }
      }
  } else {
    int h = bn >> 6;
#pragma unroll
    for (int c = 0; c < 2; ++c)
#pragma unroll
      for (int nt = 0; nt < 4; ++nt) {
        float bb = bias[bn + nt * 16 + l15];
        int d = nt * 16 + l15;
#pragma unroll
        for (int r = 0; r < 4; ++r) {
          int m = bm + w * 32 + c * 16 + quad * 4 + r;
          if (m < MROWS) {
            int b = (m >= S_) ? 1 : 0;
            int i = m - b * S_;
            vT[((size_t)(b * H_ + h) * 64 + d) * SP_ + i] = f2bf(acc[c][nt][r] + bb);
          }
        }
      }
  }
}

// ---------------------------------------------------------------------------
// Gate: ga[row] = exp(-(q_row.wg[:E] + bg)); gbv[row] = exp(-k_row.wg[E:])
// so gate(i,j) = 1/(1 + ga_i*gbv_j). 4 waves = 4 rows per block.
// ---------------------------------------------------------------------------
__global__ __launch_bounds__(256) void gate_kernel(
    const ushort_t* __restrict__ qb, const ushort_t* __restrict__ kb,
    const float* __restrict__ wg, const float* __restrict__ bgate,
    float* __restrict__ ga, float* __restrict__ gbo)
{
  int w = threadIdx.x >> 6, lane = threadIdx.x & 63;
  int row = blockIdx.x * 4 + w;
  if (row >= MROWS) return;
  const ushort_t* q = qb + (size_t)row * E_;
  const ushort_t* k = kb + (size_t)row * E_;
  float sq = 0.f, sk = 0.f;
#pragma unroll
  for (int c = 0; c < E_; c += 64) {
    sq += bf2f(q[c + lane]) * wg[c + lane];
    sk += bf2f(k[c + lane]) * wg[E_ + c + lane];
  }
#pragma unroll
  for (int o = 32; o > 0; o >>= 1) { sq += __shfl_down(sq, o); sk += __shfl_down(sk, o); }
  if (lane == 0) {
    ga[row]  = __expf(-(sq + bgate[0]));
    gbo[row] = __expf(-sk);
  }
}

// ---------------------------------------------------------------------------
// MFMA flash attention: block = 32 q-rows x (h,b); 2 waves x 16 rows;
// 1056 blocks. K and V^T staged with coalesced int4 (no transpose scatter).
// Q pre-scaled; gate = rcp(1 + ga_i*gb_j); masks folded into coords.
// ---------------------------------------------------------------------------
__global__ __launch_bounds__(128) void attn_kernel(
    const ushort_t* __restrict__ qb, const ushort_t* __restrict__ kb,
    const ushort_t* __restrict__ vT, const float* __restrict__ ga,
    const float* __restrict__ gbv_g, ushort_t* __restrict__ ahi,
    ushort_t* __restrict__ alo)
{
  __shared__ __align__(16) ushort_t Ks[64][72];   // [j][d]
  __shared__ __align__(16) ushort_t Vt[64][72];   // [d][j]
  __shared__ __align__(16) ushort_t Ps[2][16][72];
  __shared__ float gas[32];
  __shared__ float gbs[64];

  int tid = threadIdx.x;
  int lane = tid & 63, w = tid >> 6;
  int l15 = lane & 15, quad = lane >> 4;

  // middle-out q-tile order for tail balance
  int bh = blockIdx.x & 15;
  int qidx = blockIdx.x >> 4;
  int off = (qidx + 1) >> 1;
  int qt = 33 + ((qidx & 1) ? -off : off);        // covers 0..65
  int h = bh & 7, b = bh >> 3;
  int i0 = qt * 32;
  if (i0 >= S_) return;                           // qt==65: fully out of range
  const float coef = -0.5f / (512.f * 512.f);     // sigma = WIN/2

  // Q A-fragments, pre-scaled by D^-0.5 = 0.125 (exact in bf16)
  int iq = i0 + w * 16 + l15; int iqc = iq < S_ ? iq : S_ - 1;
  bf16x8 qf0 = *(const bf16x8*)&qb[((size_t)(b * S_ + iqc)) * E_ + h * 64 + quad * 8];
  bf16x8 qf1 = *(const bf16x8*)&qb[((size_t)(b * S_ + iqc)) * E_ + h * 64 + 32 + quad * 8];
#pragma unroll
  for (int e = 0; e < 8; ++e) {
    qf0[e] = (short)f2bf(bf2f((ushort_t)qf0[e]) * 0.125f);
    qf1[e] = (short)f2bf(bf2f((ushort_t)qf1[e]) * 0.125f);
  }

  if (tid < 32) {
    int i = i0 + tid;
    gas[tid] = ga[b * S_ + (i < S_ ? i : S_ - 1)];
  }
  __syncthreads();

  float av[4], di[4]; bool rv[4]; int iv[4];
#pragma unroll
  for (int r = 0; r < 4; ++r) {
    int i = i0 + w * 16 + quad * 4 + r;
    iv[r] = i; rv[r] = (i < S_);
    av[r] = gas[w * 16 + quad * 4 + r];
    di[r] = rv[r] ? (float)i : -1e5f;             // invalid row -> always masked
  }

  const f32x4 fz = {0.f, 0.f, 0.f, 0.f};
  f32x4 Ov[4] = {fz, fz, fz, fz};
  float m_run[4] = {-1e30f, -1e30f, -1e30f, -1e30f};
  float l_run[4] = {0.f, 0.f, 0.f, 0.f};

  int jt_lo = (i0 - WIN_) >> 6; if (jt_lo < 0) jt_lo = 0;
  int jt_hi = (i0 + 31 + WIN_) >> 6; if (jt_hi > NT_ - 1) jt_hi = NT_ - 1;

  int sj = tid & 63, shalf = (tid >> 6) * 32;
  const ushort_t* vrow = vT + ((size_t)(b * H_ + h) * 64 + sj) * SP_ + shalf;
  const ushort_t* kbase = kb + (size_t)b * S_ * E_ + h * 64 + shalf;

  for (int jt = jt_lo; jt <= jt_hi; ++jt) {
    int j0 = jt * 64;
    __syncthreads();
    {
      int jg = j0 + sj; int jc = jg < S_ ? jg : S_ - 1;
      const ushort_t* ksrc = kbase + (size_t)jc * E_;
      *(int4*)&Ks[sj][shalf +  0] = *(const int4*)(ksrc +  0);
      *(int4*)&Ks[sj][shalf +  8] = *(const int4*)(ksrc +  8);
      *(int4*)&Ks[sj][shalf + 16] = *(const int4*)(ksrc + 16);
      *(int4*)&Ks[sj][shalf + 24] = *(const int4*)(ksrc + 24);
      const ushort_t* vsrc = vrow + j0;            // pad cols masked via p=0
      *(int4*)&Vt[sj][shalf +  0] = *(const int4*)(vsrc +  0);
      *(int4*)&Vt[sj][shalf +  8] = *(const int4*)(vsrc +  8);
      *(int4*)&Vt[sj][shalf + 16] = *(const int4*)(vsrc + 16);
      *(int4*)&Vt[sj][shalf + 24] = *(const int4*)(vsrc + 24);
      if (tid < 64) {
        int jg2 = j0 + tid;
        gbs[tid] = gbv_g[b * S_ + (jg2 < S_ ? jg2 : S_ - 1)];
      }
    }
    __syncthreads();

    float gkb[4], djf[4];
#pragma unroll
    for (int nt = 0; nt < 4; ++nt) {
      int jv = j0 + nt * 16 + l15;
      gkb[nt] = gbs[nt * 16 + l15];
      djf[nt] = (jv < S_) ? (float)jv : 1e5f;     // invalid col -> always masked
    }

    // S = Q @ K^T (pre-scaled)
    f32x4 sf[4];
#pragma unroll
    for (int nt = 0; nt < 4; ++nt) {
      bf16x8 k0 = *(const bf16x8*)&Ks[nt * 16 + l15][quad * 8];
      bf16x8 k1 = *(const bf16x8*)&Ks[nt * 16 + l15][32 + quad * 8];
      f32x4 s = fz;
      s = MFMA16(qf0, k0, s);
      s = MFMA16(qf1, k1, s);
      sf[nt] = s;
    }

    // bias + gate + mask (single |i-j|<=WIN test handles all masks)
    float val[4][4];
#pragma unroll
    for (int nt = 0; nt < 4; ++nt) {
#pragma unroll
      for (int r = 0; r < 4; ++r) {
        float f = di[r] - djf[nt];
        float bias = f * f * coef;
        float g = fmaf(av[r], gkb[nt], 1.0f);
        float gate = __builtin_amdgcn_rcpf(g);
        float t = (sf[nt][r] + bias) * gate;
        val[nt][r] = (__builtin_fabsf(f) <= 1024.0f) ? t : -1e30f;
      }
    }

    // online softmax per row (16-lane shuffles)
    float al[4];
#pragma unroll
    for (int r = 0; r < 4; ++r) {
      float vm = fmaxf(fmaxf(val[0][r], val[1][r]), fmaxf(val[2][r], val[3][r]));
#pragma unroll
      for (int o = 1; o < 16; o <<= 1) vm = fmaxf(vm, __shfl_xor(vm, o, 16));
      float mn = fmaxf(m_run[r], vm);
      al[r] = __expf(m_run[r] - mn);
      float psum = 0.f;
#pragma unroll
      for (int nt = 0; nt < 4; ++nt) {
        float p = (val[nt][r] > -1e29f) ? __expf(val[nt][r] - mn) : 0.f;
        val[nt][r] = p;
        psum += p;
      }
#pragma unroll
      for (int o = 1; o < 16; o <<= 1) psum += __shfl_xor(psum, o, 16);
      l_run[r] = l_run[r] * al[r] + psum;
      m_run[r] = mn;
    }

    // P -> per-wave LDS (bf16), rescale O
#pragma unroll
    for (int nt = 0; nt < 4; ++nt) {
#pragma unroll
      for (int r = 0; r < 4; ++r) {
        Ps[w][quad * 4 + r][nt * 16 + l15] = f2bf(val[nt][r]);
        Ov[nt][r] = Ov[nt][r] * al[r];
      }
    }

    // O += P @ V
    bf16x8 p0 = *(const bf16x8*)&Ps[w][l15][quad * 8];
    bf16x8 p1 = *(const bf16x8*)&Ps[w][l15][32 + quad * 8];
#pragma unroll
    for (int nt = 0; nt < 4; ++nt) {
      bf16x8 v0 = *(const bf16x8*)&Vt[nt * 16 + l15][quad * 8];
      bf16x8 v1 = *(const bf16x8*)&Vt[nt * 16 + l15][32 + quad * 8];
      Ov[nt] = MFMA16(p0, v0, Ov[nt]);
      Ov[nt] = MFMA16(p1, v1, Ov[nt]);
    }
  }

  // normalize + hi/lo split store
#pragma unroll
  for (int r = 0; r < 4; ++r) {
    if (!rv[r]) continue;
    float inv = 1.f / l_run[r];
#pragma unroll
    for (int nt = 0; nt < 4; ++nt) {
      float o = Ov[nt][r] * inv;
      ushort_t hi = f2bf(o);
      size_t idx = ((size_t)(b * S_ + iv[r])) * E_ + h * 64 + nt * 16 + l15;
      ahi[idx] = hi;
      alo[idx] = f2bf(o - bf2f(hi));
    }
  }
}

// ---------------------------------------------------------------------------
// Output projection, fp32-accurate via split bf16 (3 MFMA terms)
// ---------------------------------------------------------------------------
__global__ __launch_bounds__(256) void gemm_out_kernel(
    const ushort_t* __restrict__ Ahi, const ushort_t* __restrict__ Alo,
    const ushort_t* __restrict__ Whi, const ushort_t* __restrict__ Wlo,
    const float* __restrict__ bias, float* __restrict__ C)
{
  __shared__ __align__(16) ushort_t AsH[64][40];
  __shared__ __align__(16) ushort_t AsL[64][40];
  __shared__ __align__(16) ushort_t BsH[64][40];
  __shared__ __align__(16) ushort_t BsL[64][40];
  int tid = threadIdx.x;
  int lane = tid & 63, w = tid >> 6;
  int l15 = lane & 15, quad = lane >> 4;
  int bm = blockIdx.x * 64, bn = blockIdx.y * 64;
  int srow = tid >> 2, skq = (tid & 3) * 8;
  int arow = bm + srow; if (arow >= MROWS) arow = MROWS - 1;

  const f32x4 fz = {0.f, 0.f, 0.f, 0.f};
  f32x4 acc[4] = {fz, fz, fz, fz};

  for (int k0 = 0; k0 < E_; k0 += 32) {
    __syncthreads();
    *(int4*)&AsH[srow][skq] = *(const int4*)&Ahi[(size_t)arow * E_ + k0 + skq];
    *(int4*)&AsL[srow][skq] = *(const int4*)&Alo[(size_t)arow * E_ + k0 + skq];
    *(int4*)&BsH[srow][skq] = *(const int4*)&Whi[(size_t)(bn + srow) * E_ + k0 + skq];
    *(int4*)&BsL[srow][skq] = *(const int4*)&Wlo[(size_t)(bn + srow) * E_ + k0 + skq];
    __syncthreads();
    bf16x8 ah = *(const bf16x8*)&AsH[w * 16 + l15][quad * 8];
    bf16x8 alv = *(const bf16x8*)&AsL[w * 16 + l15][quad * 8];
#pragma unroll
    for (int nt = 0; nt < 4; ++nt) {
      bf16x8 bh2 = *(const bf16x8*)&BsH[nt * 16 + l15][quad * 8];
      bf16x8 bl2 = *(const bf16x8*)&BsL[nt * 16 + l15][quad * 8];
      acc[nt] = MFMA16(ah, bh2, acc[nt]);
      acc[nt] = MFMA16(alv, bh2, acc[nt]);
      acc[nt] = MFMA16(ah, bl2, acc[nt]);
    }
  }
#pragma unroll
  for (int nt = 0; nt < 4; ++nt) {
    float bb = bias[bn + nt * 16 + l15];
#pragma unroll
    for (int r = 0; r < 4; ++r) {
      int m = bm + w * 16 + quad * 4 + r;
      if (m < MROWS)
        C[(size_t)m * E_ + bn + nt * 16 + l15] = acc[nt][r] + bb;
    }
  }
}

// ---------------------------------------------------------------------------
extern "C" void kernel_launch(void* const* d_in, const int* in_sizes, int n_in,
                              void* d_out, int out_size, void* d_ws, size_t ws_size,
                              hipStream_t stream) {
  const float* x  = (const float*)d_in[0];
  const float* Wq = (const float*)d_in[1];
  const float* bq = (const float*)d_in[2];
  const float* Wk = (const float*)d_in[3];
  const float* bk = (const float*)d_in[4];
  const float* Wv = (const float*)d_in[5];
  const float* bv = (const float*)d_in[6];
  const float* Wo = (const float*)d_in[7];
  const float* bo = (const float*)d_in[8];
  const float* wg = (const float*)d_in[9];
  const float* bg = (const float*)d_in[10];

  char* p = (char*)d_ws;
  ushort_t* xb     = (ushort_t*)p; p += (size_t)MROWS * E_ * 2;        // 4.20 MB
  ushort_t* Wt_all = (ushort_t*)p; p += (size_t)3 * E_ * E_ * 2;       // 1.57 MB
  ushort_t* WoHi   = (ushort_t*)p; p += (size_t)E_ * E_ * 2;
  ushort_t* WoLo   = (ushort_t*)p; p += (size_t)E_ * E_ * 2;
  ushort_t* qkb    = (ushort_t*)p; p += (size_t)2 * MROWS * E_ * 2;    // 8.39 MB
  ushort_t* vT     = (ushort_t*)p; p += (size_t)B_ * H_ * 64 * SP_ * 2;// 4.33 MB
  float*    gav    = (float*)p;    p += (size_t)4104 * 4;
  float*    gbvv   = (float*)p;    p += (size_t)4104 * 4;
  ushort_t* aHi    = (ushort_t*)p; p += (size_t)MROWS * E_ * 2;
  ushort_t* aLo    = (ushort_t*)p; p += (size_t)MROWS * E_ * 2;        // ~28 MB total

  hipLaunchKernelGGL(convert_x_kernel, dim3(2049), dim3(256), 0, stream, x, xb);
  hipLaunchKernelGGL(convert_w_kernel, dim3(16, 16, 4), dim3(256), 0, stream,
                     Wq, Wk, Wv, Wo, Wt_all, WoHi, WoLo);
  hipLaunchKernelGGL(gemm_qkv_kernel, dim3(33, 8, 3), dim3(256), 0, stream,
                     xb, Wt_all, bq, bk, bv, qkb, vT);
  hipLaunchKernelGGL(gate_kernel, dim3(1025), dim3(256), 0, stream,
                     qkb, qkb + (size_t)MROWS * E_, wg, bg, gav, gbvv);
  hipLaunchKernelGGL(attn_kernel, dim3(66 * 16), dim3(128), 0, stream,
                     qkb, qkb + (size_t)MROWS * E_, vT, gav, gbvv, aHi, aLo);
  hipLaunchKernelGGL(gemm_out_kernel, dim3(65, 8), dim3(256), 0, stream,
                     aHi, aLo, WoHi, WoLo, bo, (float*)d_out);
}

// Round 4
// 196.485 us; speedup vs baseline: 3.1918x; 1.1885x over previous
//
#include <hip/hip_runtime.h>
#include <cstdint>
#include <cstddef>

#define B_ 2
#define S_ 2049
#define E_ 512
#define H_ 8
#define WIN_ 1024
#define MROWS (B_*S_)     // 4098
#define SP_ 2176          // padded seq for vT rows (17*128)
#define GBUFN 4104

typedef unsigned short ushort_t;
typedef __attribute__((ext_vector_type(8))) short bf16x8;   // 8 bf16 (4 VGPRs)
typedef __attribute__((ext_vector_type(4))) float f32x4;

#define MFMA16(a,b,c) __builtin_amdgcn_mfma_f32_16x16x32_bf16(a,b,c,0,0,0)

__device__ __forceinline__ ushort_t f2bf(float f) {          // RNE fp32->bf16
  unsigned int u = __float_as_uint(f);
  u += 0x7fffu + ((u >> 16) & 1u);
  return (ushort_t)(u >> 16);
}
__device__ __forceinline__ float bf2f(ushort_t h) {
  return __uint_as_float(((unsigned int)h) << 16);
}

// ---------------------------------------------------------------------------
// x fp32 -> bf16 (exact grid: 2049 blocks x 256 float4)
// ---------------------------------------------------------------------------
__global__ __launch_bounds__(256) void convert_x_kernel(
    const float* __restrict__ x, ushort_t* __restrict__ xb)
{
  int idx = blockIdx.x * 256 + threadIdx.x;
  float4 v = ((const float4*)x)[idx];
  ushort4 o;
  o.x = f2bf(v.x); o.y = f2bf(v.y); o.z = f2bf(v.z); o.w = f2bf(v.w);
  ((ushort4*)xb)[idx] = o;
}

// ---------------------------------------------------------------------------
// W [k][n] fp32 -> Wt [n][k] bf16 (z<3: Wq/Wk/Wv; z==3: Wo -> WoHi)
// ---------------------------------------------------------------------------
__global__ __launch_bounds__(256) void convert_w_kernel(
    const float* __restrict__ W0, const float* __restrict__ W1,
    const float* __restrict__ W2, const float* __restrict__ W3,
    ushort_t* __restrict__ Wt_all, ushort_t* __restrict__ WoHi)
{
  __shared__ float tile[32][33];
  int z = blockIdx.z;
  const float* W = (z == 0) ? W0 : (z == 1) ? W1 : (z == 2) ? W2 : W3;
  int k0 = blockIdx.x * 32, n0 = blockIdx.y * 32;
  int r = threadIdx.x >> 5, c = threadIdx.x & 31;
#pragma unroll
  for (int i = 0; i < 4; ++i) {
    int rr = r + i * 8;
    tile[rr][c] = W[(size_t)(k0 + rr) * E_ + n0 + c];
  }
  __syncthreads();
#pragma unroll
  for (int i = 0; i < 4; ++i) {
    int rr = r + i * 8;
    float v = tile[c][rr];                       // = W[k0+c][n0+rr]
    size_t dst = (size_t)(n0 + rr) * E_ + k0 + c;
    if (z < 3) Wt_all[(size_t)z * E_ * E_ + dst] = f2bf(v);
    else       WoHi[dst] = f2bf(v);
  }
}

// ---------------------------------------------------------------------------
// QKV projection, 128x64 tile, 4 waves x (32m x 64n), BK=32, reg-prefetch.
// z<2 (q,k): row-major bf16 + gate partial dots (atomicAdd).
// z==2 (v): transposed store to vT[b][h][d][s].
// ---------------------------------------------------------------------------
__global__ __launch_bounds__(256) void gemm_qkv_kernel(
    const ushort_t* __restrict__ xb, const ushort_t* __restrict__ Wt_all,
    const float* __restrict__ bq, const float* __restrict__ bk,
    const float* __restrict__ bv, const float* __restrict__ wg,
    ushort_t* __restrict__ qkb, ushort_t* __restrict__ vT,
    float* __restrict__ gq_acc, float* __restrict__ gk_acc)
{
  __shared__ __align__(16) ushort_t As[128][40];
  __shared__ __align__(16) ushort_t Bs[64][40];
  int tid = threadIdx.x;
  int lane = tid & 63, w = tid >> 6;
  int l15 = lane & 15, quad = lane >> 4;
  int z = blockIdx.z;
  const ushort_t* Wt = Wt_all + (size_t)z * E_ * E_;
  const float* bias = (z == 0) ? bq : (z == 1) ? bk : bv;
  int bm = blockIdx.x * 128, bn = blockIdx.y * 64;

  int ar = tid >> 2, akq = (tid & 3) * 8;
  int am0 = bm + ar;      if (am0 >= MROWS) am0 = MROWS - 1;
  int am1 = bm + ar + 64; if (am1 >= MROWS) am1 = MROWS - 1;

  const f32x4 fz = {0.f, 0.f, 0.f, 0.f};
  f32x4 acc[2][4] = {{fz, fz, fz, fz}, {fz, fz, fz, fz}};

  int4 pa0 = *(const int4*)&xb[(size_t)am0 * E_ + akq];
  int4 pa1 = *(const int4*)&xb[(size_t)am1 * E_ + akq];
  int4 pb  = *(const int4*)&Wt[(size_t)(bn + ar) * E_ + akq];

  for (int k0 = 0; k0 < E_; k0 += 32) {
    __syncthreads();
    int kn = (k0 + 32 < E_) ? (k0 + 32) : k0;
    int4 na0 = *(const int4*)&xb[(size_t)am0 * E_ + kn + akq];
    int4 na1 = *(const int4*)&xb[(size_t)am1 * E_ + kn + akq];
    int4 nb  = *(const int4*)&Wt[(size_t)(bn + ar) * E_ + kn + akq];
    *(int4*)&As[ar][akq]      = pa0;
    *(int4*)&As[ar + 64][akq] = pa1;
    *(int4*)&Bs[ar][akq]      = pb;
    __syncthreads();
    bf16x8 a0 = *(const bf16x8*)&As[w * 32 + l15][quad * 8];
    bf16x8 a1 = *(const bf16x8*)&As[w * 32 + 16 + l15][quad * 8];
#pragma unroll
    for (int nt = 0; nt < 4; ++nt) {
      bf16x8 bfr = *(const bf16x8*)&Bs[nt * 16 + l15][quad * 8];
      acc[0][nt] = MFMA16(a0, bfr, acc[0][nt]);
      acc[1][nt] = MFMA16(a1, bfr, acc[1][nt]);
    }
    pa0 = na0; pa1 = na1; pb = nb;
  }

  float bb[4];
#pragma unroll
  for (int nt = 0; nt < 4; ++nt) bb[nt] = bias[bn + nt * 16 + l15];

  if (z < 2) {
    ushort_t* C = qkb + (size_t)z * MROWS * E_;
#pragma unroll
    for (int c = 0; c < 2; ++c)
#pragma unroll
      for (int nt = 0; nt < 4; ++nt)
#pragma unroll
        for (int r = 0; r < 4; ++r) {
          int m = bm + w * 32 + c * 16 + quad * 4 + r;
          if (m < MROWS)
            C[(size_t)m * E_ + bn + nt * 16 + l15] = f2bf(acc[c][nt][r] + bb[nt]);
        }
    // fused gate partial dot over this block's 64 cols
    const float* wgp = wg + (size_t)z * E_;
    float wv[4];
#pragma unroll
    for (int nt = 0; nt < 4; ++nt) wv[nt] = wgp[bn + nt * 16 + l15];
    float* gacc = (z == 0) ? gq_acc : gk_acc;
#pragma unroll
    for (int c = 0; c < 2; ++c)
#pragma unroll
      for (int r = 0; r < 4; ++r) {
        float s = 0.f;
#pragma unroll
        for (int nt = 0; nt < 4; ++nt) s = fmaf(acc[c][nt][r] + bb[nt], wv[nt], s);
        s += __shfl_xor(s, 1, 16); s += __shfl_xor(s, 2, 16);
        s += __shfl_xor(s, 4, 16); s += __shfl_xor(s, 8, 16);
        int m = bm + w * 32 + c * 16 + quad * 4 + r;
        if (l15 == 0 && m < MROWS) atomicAdd(&gacc[m], s);
      }
  } else {
    int h = bn >> 6;
#pragma unroll
    for (int c = 0; c < 2; ++c)
#pragma unroll
      for (int nt = 0; nt < 4; ++nt) {
        int d = nt * 16 + l15;
#pragma unroll
        for (int r = 0; r < 4; ++r) {
          int m = bm + w * 32 + c * 16 + quad * 4 + r;
          if (m < MROWS) {
            int b = (m >= S_) ? 1 : 0;
            int i = m - b * S_;
            vT[((size_t)(b * H_ + h) * 64 + d) * SP_ + i] = f2bf(acc[c][nt][r] + bb[nt]);
          }
        }
      }
  }
}

// ---------------------------------------------------------------------------
// MFMA flash attention, S^T formulation. Block = 64 q-rows x (h,b), 4 waves
// x 16 rows, 128-col j-tiles. Per thread: one q-row (i=l15), 32 scores/tile.
// Softmax: in-thread reduce + 2 shfl_xor. P packed b64 -> LDS. Reg-prefetch
// staging for K and V^T. Gates preloaded (exp applied) to LDS.
// ---------------------------------------------------------------------------
__global__ __launch_bounds__(256) void attn_kernel(
    const ushort_t* __restrict__ qb, const ushort_t* __restrict__ kb,
    const ushort_t* __restrict__ vT, const float* __restrict__ gq_raw,
    const float* __restrict__ gk_raw, const float* __restrict__ bgate,
    ushort_t* __restrict__ ahi, ushort_t* __restrict__ alo)
{
  __shared__ __align__(16) ushort_t Ks[128][72];    // [j][d]
  __shared__ __align__(16) ushort_t Vt[64][136];    // [d][j]
  __shared__ __align__(16) ushort_t Ps[4][16][136]; // per-wave P [i][j]
  __shared__ float als[4][16];
  __shared__ float lls[4][16];
  __shared__ float gbs[2176];

  int tid = threadIdx.x;
  int lane = tid & 63, w = tid >> 6;
  int l15 = lane & 15, quad = lane >> 4;

  // middle-out q-tile order (heavy central tiles dispatch first)
  int bh = blockIdx.x & 15;
  int qidx = blockIdx.x >> 4;
  int off = (qidx + 1) >> 1;
  int qt = 16 + ((qidx & 1) ? -off : off);          // 0..32
  int h = bh & 7, b = bh >> 3;
  int i0 = qt * 64;
  const float coef = -0.5f / (512.f * 512.f);       // sigma = WIN/2

  // per-thread q-row
  int i = i0 + w * 16 + l15;
  int ic = (i < S_) ? i : S_ - 1;
  bf16x8 qf0 = *(const bf16x8*)&qb[((size_t)(b * S_ + ic)) * E_ + h * 64 + quad * 8];
  bf16x8 qf1 = *(const bf16x8*)&qb[((size_t)(b * S_ + ic)) * E_ + h * 64 + 32 + quad * 8];
#pragma unroll
  for (int e = 0; e < 8; ++e) {                     // pre-scale by D^-0.5 (exact)
    qf0[e] = (short)f2bf(bf2f((ushort_t)qf0[e]) * 0.125f);
    qf1[e] = (short)f2bf(bf2f((ushort_t)qf1[e]) * 0.125f);
  }
  float av = __expf(-(gq_raw[b * S_ + ic] + bgate[0]));
  float fdi = (i < S_) ? (float)i : -1e5f;

  int jt_lo = i0 - WIN_; if (jt_lo < 0) jt_lo = 0; jt_lo >>= 7;
  int jhi = i0 + 63 + WIN_; if (jhi > S_ - 1) jhi = S_ - 1;
  int jt_hi = jhi >> 7;
  int jbase = jt_lo << 7;
  int nwin = (jt_hi - jt_lo + 1) << 7;              // <= 2176

  // preload gate-k table (exp applied)
  for (int tt = tid; tt < nwin; tt += 256) {
    int j = jbase + tt; int jc = (j < S_) ? j : S_ - 1;
    gbs[tt] = __expf(-gk_raw[b * S_ + jc]);
  }

  // staging maps
  int krow = tid >> 1, kcol = (tid & 1) * 32;       // Ks: 128 x 64
  int vrow = tid >> 2, vcol = (tid & 3) * 32;       // Vt: 64 x 128
  const ushort_t* kb_base = kb + (size_t)b * S_ * E_ + h * 64 + kcol;
  const ushort_t* vT_base = vT + ((size_t)(b * H_ + h) * 64 + vrow) * SP_;

  int4 kc0, kc1, kc2, kc3, vc0, vc1, vc2, vc3;
  {
    int jc = (jbase + krow < S_) ? jbase + krow : S_ - 1;
    const int4* kp = (const int4*)(kb_base + (size_t)jc * E_);
    kc0 = kp[0]; kc1 = kp[1]; kc2 = kp[2]; kc3 = kp[3];
    const int4* vp = (const int4*)(vT_base + jbase + vcol);
    vc0 = vp[0]; vc1 = vp[1]; vc2 = vp[2]; vc3 = vp[3];
  }

  const f32x4 fz = {0.f, 0.f, 0.f, 0.f};
  f32x4 Ov[4] = {fz, fz, fz, fz};
  float m_run = -1e30f, l_run = 0.f;

  for (int jt = jt_lo; jt <= jt_hi; ++jt) {
    int j0 = jt << 7;
    __syncthreads();
    // prefetch next tile (issued before LDS commit; independent regs)
    int jn = (jt < jt_hi) ? (jt + 1) << 7 : j0;
    int jcn = (jn + krow < S_) ? jn + krow : S_ - 1;
    const int4* kp = (const int4*)(kb_base + (size_t)jcn * E_);
    int4 nk0 = kp[0], nk1 = kp[1], nk2 = kp[2], nk3 = kp[3];
    const int4* vp = (const int4*)(vT_base + jn + vcol);
    int4 nv0 = vp[0], nv1 = vp[1], nv2 = vp[2], nv3 = vp[3];
    // commit current tile
    *(int4*)&Ks[krow][kcol + 0]  = kc0; *(int4*)&Ks[krow][kcol + 8]  = kc1;
    *(int4*)&Ks[krow][kcol + 16] = kc2; *(int4*)&Ks[krow][kcol + 24] = kc3;
    *(int4*)&Vt[vrow][vcol + 0]  = vc0; *(int4*)&Vt[vrow][vcol + 8]  = vc1;
    *(int4*)&Vt[vrow][vcol + 16] = vc2; *(int4*)&Vt[vrow][vcol + 24] = vc3;
    __syncthreads();

    // S^T = K . Q^T : A = K rows (j), B = Q regs -> lane holds one (i=l15)
    f32x4 st[8];
#pragma unroll
    for (int nt = 0; nt < 8; ++nt) {
      bf16x8 kf0 = *(const bf16x8*)&Ks[nt * 16 + l15][quad * 8];
      bf16x8 kf1 = *(const bf16x8*)&Ks[nt * 16 + l15][32 + quad * 8];
      f32x4 s = MFMA16(kf0, qf0, fz);
      st[nt] = MFMA16(kf1, qf1, s);
    }

    // bias + gate + mask, track row max (in-thread + 2 swizzles)
    float vm = -1e30f;
#pragma unroll
    for (int nt = 0; nt < 8; ++nt) {
      f32x4 g4 = *(const f32x4*)&gbs[(j0 - jbase) + nt * 16 + quad * 4];
#pragma unroll
      for (int r = 0; r < 4; ++r) {
        int j = j0 + nt * 16 + quad * 4 + r;
        float fj = (j < S_) ? (float)j : 1e5f;
        float f = fdi - fj;
        float gate = __builtin_amdgcn_rcpf(fmaf(av, g4[r], 1.f));
        float t = fmaf(f * f, coef, st[nt][r]) * gate;
        t = (__builtin_fabsf(f) <= 1024.f) ? t : -1e30f;
        st[nt][r] = t;
        vm = fmaxf(vm, t);
      }
    }
    vm = fmaxf(vm, __shfl_xor(vm, 16));
    vm = fmaxf(vm, __shfl_xor(vm, 32));
    float mn = fmaxf(m_run, vm);
    float alx = __expf(m_run - mn);
    float ps = 0.f;
#pragma unroll
    for (int nt = 0; nt < 8; ++nt)
#pragma unroll
      for (int r = 0; r < 4; ++r) {
        float e = __expf(st[nt][r] - mn);
        st[nt][r] = e;
        ps += e;
      }
    ps += __shfl_xor(ps, 16);
    ps += __shfl_xor(ps, 32);
    l_run = l_run * alx + ps;
    m_run = mn;

    if (lane < 16) als[w][lane] = alx;
    // pack P rows: P[i=l15][j], 4 consecutive j per write
#pragma unroll
    for (int nt = 0; nt < 8; ++nt) {
      unsigned int lo = (unsigned int)f2bf(st[nt][0]) | ((unsigned int)f2bf(st[nt][1]) << 16);
      unsigned int hi = (unsigned int)f2bf(st[nt][2]) | ((unsigned int)f2bf(st[nt][3]) << 16);
      uint2 pk; pk.x = lo; pk.y = hi;
      *(uint2*)&Ps[w][l15][nt * 16 + quad * 4] = pk;
    }
    f32x4 al4 = *(const f32x4*)&als[w][quad * 4];
#pragma unroll
    for (int nt = 0; nt < 4; ++nt) Ov[nt] *= al4;

    // O += P @ V
    bf16x8 pf[4];
#pragma unroll
    for (int kk = 0; kk < 4; ++kk)
      pf[kk] = *(const bf16x8*)&Ps[w][l15][kk * 32 + quad * 8];
#pragma unroll
    for (int nt = 0; nt < 4; ++nt) {
#pragma unroll
      for (int kk = 0; kk < 4; ++kk) {
        bf16x8 vf = *(const bf16x8*)&Vt[nt * 16 + l15][kk * 32 + quad * 8];
        Ov[nt] = MFMA16(pf[kk], vf, Ov[nt]);
      }
    }
    kc0 = nk0; kc1 = nk1; kc2 = nk2; kc3 = nk3;
    vc0 = nv0; vc1 = nv1; vc2 = nv2; vc3 = nv3;
  }

  if (lane < 16) lls[w][lane] = 1.f / l_run;
  f32x4 inv4 = *(const f32x4*)&lls[w][quad * 4];
#pragma unroll
  for (int r = 0; r < 4; ++r) {
    int irow = i0 + w * 16 + quad * 4 + r;
    if (irow < S_) {
#pragma unroll
      for (int nt = 0; nt < 4; ++nt) {
        float o = Ov[nt][r] * inv4[r];
        ushort_t hv = f2bf(o);
        size_t idx = ((size_t)(b * S_ + irow)) * E_ + h * 64 + nt * 16 + l15;
        ahi[idx] = hv;
        alo[idx] = f2bf(o - bf2f(hv));
      }
    }
  }
}

// ---------------------------------------------------------------------------
// Output projection, 2-term split: C = (Ahi + Alo) @ Whi + bias (fp32 out)
// ---------------------------------------------------------------------------
__global__ __launch_bounds__(256) void gemm_out_kernel(
    const ushort_t* __restrict__ Ahi, const ushort_t* __restrict__ Alo,
    const ushort_t* __restrict__ Whi, const float* __restrict__ bias,
    float* __restrict__ C)
{
  __shared__ __align__(16) ushort_t AsH[64][40];
  __shared__ __align__(16) ushort_t AsL[64][40];
  __shared__ __align__(16) ushort_t BsH[64][40];
  int tid = threadIdx.x;
  int lane = tid & 63, w = tid >> 6;
  int l15 = lane & 15, quad = lane >> 4;
  int bm = blockIdx.x * 64, bn = blockIdx.y * 64;
  int srow = tid >> 2, skq = (tid & 3) * 8;
  int arow = bm + srow; if (arow >= MROWS) arow = MROWS - 1;

  const f32x4 fz = {0.f, 0.f, 0.f, 0.f};
  f32x4 acc[4] = {fz, fz, fz, fz};

  int4 ph = *(const int4*)&Ahi[(size_t)arow * E_ + skq];
  int4 pl = *(const int4*)&Alo[(size_t)arow * E_ + skq];
  int4 pb = *(const int4*)&Whi[(size_t)(bn + srow) * E_ + skq];

  for (int k0 = 0; k0 < E_; k0 += 32) {
    __syncthreads();
    int kn = (k0 + 32 < E_) ? (k0 + 32) : k0;
    int4 nh = *(const int4*)&Ahi[(size_t)arow * E_ + kn + skq];
    int4 nl = *(const int4*)&Alo[(size_t)arow * E_ + kn + skq];
    int4 nb = *(const int4*)&Whi[(size_t)(bn + srow) * E_ + kn + skq];
    *(int4*)&AsH[srow][skq] = ph;
    *(int4*)&AsL[srow][skq] = pl;
    *(int4*)&BsH[srow][skq] = pb;
    __syncthreads();
    bf16x8 ah = *(const bf16x8*)&AsH[w * 16 + l15][quad * 8];
    bf16x8 al = *(const bf16x8*)&AsL[w * 16 + l15][quad * 8];
#pragma unroll
    for (int nt = 0; nt < 4; ++nt) {
      bf16x8 bh = *(const bf16x8*)&BsH[nt * 16 + l15][quad * 8];
      acc[nt] = MFMA16(ah, bh, acc[nt]);
      acc[nt] = MFMA16(al, bh, acc[nt]);
    }
    ph = nh; pl = nl; pb = nb;
  }
#pragma unroll
  for (int nt = 0; nt < 4; ++nt) {
    float bb = bias[bn + nt * 16 + l15];
#pragma unroll
    for (int r = 0; r < 4; ++r) {
      int m = bm + w * 16 + quad * 4 + r;
      if (m < MROWS)
        C[(size_t)m * E_ + bn + nt * 16 + l15] = acc[nt][r] + bb;
    }
  }
}

// ---------------------------------------------------------------------------
extern "C" void kernel_launch(void* const* d_in, const int* in_sizes, int n_in,
                              void* d_out, int out_size, void* d_ws, size_t ws_size,
                              hipStream_t stream) {
  const float* x  = (const float*)d_in[0];
  const float* Wq = (const float*)d_in[1];
  const float* bq = (const float*)d_in[2];
  const float* Wk = (const float*)d_in[3];
  const float* bk = (const float*)d_in[4];
  const float* Wv = (const float*)d_in[5];
  const float* bv = (const float*)d_in[6];
  const float* Wo = (const float*)d_in[7];
  const float* bo = (const float*)d_in[8];
  const float* wg = (const float*)d_in[9];
  const float* bg = (const float*)d_in[10];

  char* p = (char*)d_ws;
  ushort_t* xb     = (ushort_t*)p; p += (size_t)MROWS * E_ * 2;          // 4.20 MB
  ushort_t* Wt_all = (ushort_t*)p; p += (size_t)3 * E_ * E_ * 2;         // 1.57 MB
  ushort_t* WoHi   = (ushort_t*)p; p += (size_t)E_ * E_ * 2;             // 0.52 MB
  ushort_t* qkb    = (ushort_t*)p; p += (size_t)2 * MROWS * E_ * 2;      // 8.39 MB
  ushort_t* vT     = (ushort_t*)p; p += (size_t)B_ * H_ * 64 * SP_ * 2;  // 4.46 MB
  float*    gq_acc = (float*)p;    p += (size_t)GBUFN * 4;
  float*    gk_acc = (float*)p;    p += (size_t)GBUFN * 4;
  ushort_t* aHi    = (ushort_t*)p; p += (size_t)MROWS * E_ * 2;
  ushort_t* aLo    = (ushort_t*)p; p += (size_t)MROWS * E_ * 2;          // ~28 MB

  hipLaunchKernelGGL(convert_x_kernel, dim3(2049), dim3(256), 0, stream, x, xb);
  hipLaunchKernelGGL(convert_w_kernel, dim3(16, 16, 4), dim3(256), 0, stream,
                     Wq, Wk, Wv, Wo, Wt_all, WoHi);
  hipMemsetAsync(gq_acc, 0, 2 * (size_t)GBUFN * 4, stream);
  hipLaunchKernelGGL(gemm_qkv_kernel, dim3(33, 8, 3), dim3(256), 0, stream,
                     xb, Wt_all, bq, bk, bv, wg, qkb, vT, gq_acc, gk_acc);
  hipLaunchKernelGGL(attn_kernel, dim3(33 * 16), dim3(256), 0, stream,
                     qkb, qkb + (size_t)MROWS * E_, vT, gq_acc, gk_acc, bg, aHi, aLo);
  hipLaunchKernelGGL(gemm_out_kernel, dim3(65, 8), dim3(256), 0, stream,
                     aHi, aLo, WoHi, bo, (float*)d_out);
}

// Round 5
// 177.628 us; speedup vs baseline: 3.5306x; 1.1062x over previous
//
#include <hip/hip_runtime.h>
#include <cstdint>
#include <cstddef>

#define B_ 2
#define S_ 2049
#define E_ 512
#define H_ 8
#define WIN_ 1024
#define MROWS (B_*S_)     // 4098
#define SP_ 2176          // padded seq for vT rows
#define GBUFN 4104

typedef unsigned short ushort_t;
typedef __attribute__((ext_vector_type(8))) short bf16x8;   // 8 bf16 (4 VGPRs)
typedef __attribute__((ext_vector_type(4))) float f32x4;

#define MFMA16(a,b,c) __builtin_amdgcn_mfma_f32_16x16x32_bf16(a,b,c,0,0,0)

__device__ __forceinline__ ushort_t f2bf(float f) {          // RNE fp32->bf16
  unsigned int u = __float_as_uint(f);
  u += 0x7fffu + ((u >> 16) & 1u);
  return (ushort_t)(u >> 16);
}
__device__ __forceinline__ float bf2f(ushort_t h) {
  return __uint_as_float(((unsigned int)h) << 16);
}

// ---------------------------------------------------------------------------
// One launch: blocks [0,2049) convert x fp32->bf16; blocks [2049,3073) convert
// W [k][n] fp32 -> Wt [n][k] bf16 (z<3: Wq/Wk/Wv, z==3: Wo->WoHi).
// ---------------------------------------------------------------------------
__global__ __launch_bounds__(256) void convert_all_kernel(
    const float* __restrict__ x, const float* __restrict__ W0,
    const float* __restrict__ W1, const float* __restrict__ W2,
    const float* __restrict__ W3, ushort_t* __restrict__ xb,
    ushort_t* __restrict__ Wt_all, ushort_t* __restrict__ WoHi)
{
  __shared__ float tile[32][33];
  int bid = blockIdx.x;
  if (bid < 2049) {
    int idx = bid * 256 + threadIdx.x;
    float4 v = ((const float4*)x)[idx];
    ushort4 o;
    o.x = f2bf(v.x); o.y = f2bf(v.y); o.z = f2bf(v.z); o.w = f2bf(v.w);
    ((ushort4*)xb)[idx] = o;
    return;
  }
  int wid = bid - 2049;
  int z = wid >> 8, rem = wid & 255;
  const float* W = (z == 0) ? W0 : (z == 1) ? W1 : (z == 2) ? W2 : W3;
  int k0 = (rem >> 4) * 32, n0 = (rem & 15) * 32;
  int r = threadIdx.x >> 5, c = threadIdx.x & 31;
#pragma unroll
  for (int i = 0; i < 4; ++i) {
    int rr = r + i * 8;
    tile[rr][c] = W[(size_t)(k0 + rr) * E_ + n0 + c];
  }
  __syncthreads();
#pragma unroll
  for (int i = 0; i < 4; ++i) {
    int rr = r + i * 8;
    float v = tile[c][rr];                       // = W[k0+c][n0+rr]
    size_t dst = (size_t)(n0 + rr) * E_ + k0 + c;
    if (z < 3) Wt_all[(size_t)z * E_ * E_ + dst] = f2bf(v);
    else       WoHi[dst] = f2bf(v);
  }
}

// ---------------------------------------------------------------------------
// QKV projection, 128x128 tile, 2x2 waves (64x64 each), BK=32, reg-prefetch.
// z<2 (q,k): row-major bf16 + fused gate partial dots (atomicAdd).
// z==2 (v): transposed store to vT[b][h][d][s].
// ---------------------------------------------------------------------------
__global__ __launch_bounds__(256) void gemm_qkv_kernel(
    const ushort_t* __restrict__ xb, const ushort_t* __restrict__ Wt_all,
    const float* __restrict__ bq, const float* __restrict__ bk,
    const float* __restrict__ bv, const float* __restrict__ wg,
    ushort_t* __restrict__ qkb, ushort_t* __restrict__ vT,
    float* __restrict__ gq_acc, float* __restrict__ gk_acc)
{
  __shared__ __align__(16) ushort_t As[128][40];
  __shared__ __align__(16) ushort_t Bs[128][40];
  int tid = threadIdx.x;
  int lane = tid & 63, w = tid >> 6;
  int l15 = lane & 15, quad = lane >> 4;
  int wm = (w & 1) * 64, wn = (w >> 1) * 64;
  int z = blockIdx.z;
  const ushort_t* Wt = Wt_all + (size_t)z * E_ * E_;
  const float* bias = (z == 0) ? bq : (z == 1) ? bk : bv;
  int bm = blockIdx.x * 128, bn = blockIdx.y * 128;

  int ar = tid >> 1, ac = (tid & 1) * 16;
  int am = bm + ar; if (am >= MROWS) am = MROWS - 1;
  const ushort_t* ap = xb + (size_t)am * E_ + ac;
  const ushort_t* bp = Wt + (size_t)(bn + ar) * E_ + ac;

  const f32x4 fz = {0.f, 0.f, 0.f, 0.f};
  f32x4 acc[4][4];
#pragma unroll
  for (int mt = 0; mt < 4; ++mt)
#pragma unroll
    for (int nt = 0; nt < 4; ++nt) acc[mt][nt] = fz;

  int4 pa0 = *(const int4*)ap, pa1 = *(const int4*)(ap + 8);
  int4 pb0 = *(const int4*)bp, pb1 = *(const int4*)(bp + 8);

  for (int k0 = 0; k0 < E_; k0 += 32) {
    __syncthreads();
    int kn = (k0 + 32 < E_) ? (k0 + 32) : k0;
    int4 na0 = *(const int4*)(ap + kn), na1 = *(const int4*)(ap + kn + 8);
    int4 nb0 = *(const int4*)(bp + kn), nb1 = *(const int4*)(bp + kn + 8);
    *(int4*)&As[ar][ac] = pa0; *(int4*)&As[ar][ac + 8] = pa1;
    *(int4*)&Bs[ar][ac] = pb0; *(int4*)&Bs[ar][ac + 8] = pb1;
    __syncthreads();
    bf16x8 a[4], bfr[4];
#pragma unroll
    for (int mt = 0; mt < 4; ++mt) a[mt] = *(const bf16x8*)&As[wm + mt * 16 + l15][quad * 8];
#pragma unroll
    for (int nt = 0; nt < 4; ++nt) bfr[nt] = *(const bf16x8*)&Bs[wn + nt * 16 + l15][quad * 8];
#pragma unroll
    for (int mt = 0; mt < 4; ++mt)
#pragma unroll
      for (int nt = 0; nt < 4; ++nt)
        acc[mt][nt] = MFMA16(a[mt], bfr[nt], acc[mt][nt]);
    pa0 = na0; pa1 = na1; pb0 = nb0; pb1 = nb1;
  }

  float bb[4];
#pragma unroll
  for (int nt = 0; nt < 4; ++nt) bb[nt] = bias[bn + wn + nt * 16 + l15];

  if (z < 2) {
    ushort_t* C = qkb + (size_t)z * MROWS * E_;
#pragma unroll
    for (int mt = 0; mt < 4; ++mt)
#pragma unroll
      for (int nt = 0; nt < 4; ++nt)
#pragma unroll
        for (int r = 0; r < 4; ++r) {
          int m = bm + wm + mt * 16 + quad * 4 + r;
          if (m < MROWS)
            C[(size_t)m * E_ + bn + wn + nt * 16 + l15] = f2bf(acc[mt][nt][r] + bb[nt]);
        }
    // fused gate partial dots over this block's 128 cols
    const float* wgp = wg + (size_t)z * E_;
    float wv[4];
#pragma unroll
    for (int nt = 0; nt < 4; ++nt) wv[nt] = wgp[bn + wn + nt * 16 + l15];
    float* gacc = (z == 0) ? gq_acc : gk_acc;
#pragma unroll
    for (int mt = 0; mt < 4; ++mt)
#pragma unroll
      for (int r = 0; r < 4; ++r) {
        float s = 0.f;
#pragma unroll
        for (int nt = 0; nt < 4; ++nt) s = fmaf(acc[mt][nt][r] + bb[nt], wv[nt], s);
        s += __shfl_xor(s, 1, 16); s += __shfl_xor(s, 2, 16);
        s += __shfl_xor(s, 4, 16); s += __shfl_xor(s, 8, 16);
        int m = bm + wm + mt * 16 + quad * 4 + r;
        if (l15 == 0 && m < MROWS) atomicAdd(&gacc[m], s);
      }
  } else {
#pragma unroll
    for (int mt = 0; mt < 4; ++mt)
#pragma unroll
      for (int nt = 0; nt < 4; ++nt) {
        int dg = bn + wn + nt * 16 + l15;
        int h = dg >> 6, d = dg & 63;
#pragma unroll
        for (int r = 0; r < 4; ++r) {
          int m = bm + wm + mt * 16 + quad * 4 + r;
          if (m < MROWS) {
            int b = (m >= S_) ? 1 : 0;
            int i = m - b * S_;
            vT[((size_t)(b * H_ + h) * 64 + d) * SP_ + i] = f2bf(acc[mt][nt][r] + bb[nt]);
          }
        }
      }
  }
}

// ---------------------------------------------------------------------------
// MFMA flash attention, S^T form, NO max-tracking (scores bounded: |s|<=1.6,
// gate in (0,1), bias<=0 -> exp never overflows; masked lanes exp(-1e30)=0).
// Block = 64 q-rows x (h,b), 4 waves x 16 rows, 64-col j-tiles, fast/slow
// mask paths, reg-prefetch staging. LDS 36.6 KB -> 4 blocks/CU.
// ---------------------------------------------------------------------------
__global__ __launch_bounds__(256) void attn_kernel(
    const ushort_t* __restrict__ qb, const ushort_t* __restrict__ kb,
    const ushort_t* __restrict__ vT, const float* __restrict__ gq_raw,
    const float* __restrict__ gk_raw, const float* __restrict__ bgate,
    ushort_t* __restrict__ ahi, ushort_t* __restrict__ alo)
{
  __shared__ __align__(16) ushort_t Ks[64][72];    // [j][d]
  __shared__ __align__(16) ushort_t Vt[64][72];    // [d][j]
  __shared__ __align__(16) ushort_t Ps[4][16][72]; // per-wave P [i][j]
  __shared__ float lls[4][16];
  __shared__ float gbs[2176];

  int tid = threadIdx.x;
  int lane = tid & 63, w = tid >> 6;
  int l15 = lane & 15, quad = lane >> 4;

  // middle-out q-tile order (heavy central tiles dispatch first)
  int bh = blockIdx.x & 15;
  int qidx = blockIdx.x >> 4;
  int off = (qidx + 1) >> 1;
  int qt = 16 + ((qidx & 1) ? -off : off);          // 0..32
  int h = bh & 7, b = bh >> 3;
  int i0 = qt * 64;
  const float coef = -0.5f / (512.f * 512.f);       // sigma = WIN/2

  // per-thread q-row
  int i = i0 + w * 16 + l15;
  int ic = (i < S_) ? i : S_ - 1;
  bf16x8 qf0 = *(const bf16x8*)&qb[((size_t)(b * S_ + ic)) * E_ + h * 64 + quad * 8];
  bf16x8 qf1 = *(const bf16x8*)&qb[((size_t)(b * S_ + ic)) * E_ + h * 64 + 32 + quad * 8];
#pragma unroll
  for (int e = 0; e < 8; ++e) {                     // pre-scale by D^-0.5 (exact)
    qf0[e] = (short)f2bf(bf2f((ushort_t)qf0[e]) * 0.125f);
    qf1[e] = (short)f2bf(bf2f((ushort_t)qf1[e]) * 0.125f);
  }
  float av = __expf(-(gq_raw[b * S_ + ic] + bgate[0]));
  float fdi = (i < S_) ? (float)i : -1e5f;

  int jlo = i0 - WIN_; if (jlo < 0) jlo = 0;
  int jt_lo = jlo >> 6;
  int jhi = i0 + 63 + WIN_; if (jhi > S_ - 1) jhi = S_ - 1;
  int jt_hi = jhi >> 6;
  int jbase = jt_lo << 6;
  int nwin = (jt_hi - jt_lo + 1) << 6;              // <= 2176

  for (int tt = tid; tt < nwin; tt += 256) {
    int j = jbase + tt; int jc = (j < S_) ? j : S_ - 1;
    gbs[tt] = __expf(-gk_raw[b * S_ + jc]);
  }

  // staging maps: K rows=j, V^T rows=d; both 64x64, 2 int4 per thread
  int srow = tid >> 2, scol = (tid & 3) * 16;
  const ushort_t* kb_base = kb + (size_t)b * S_ * E_ + h * 64 + scol;
  const ushort_t* vb_base = vT + ((size_t)(b * H_ + h) * 64 + srow) * SP_ + scol;

  int4 ka0, ka1, va0, va1;
  {
    int jc0 = jbase + srow; if (jc0 > S_ - 1) jc0 = S_ - 1;
    const int4* kp = (const int4*)(kb_base + (size_t)jc0 * E_);
    ka0 = kp[0]; ka1 = kp[1];
    const int4* vp = (const int4*)(vb_base + jbase);
    va0 = vp[0]; va1 = vp[1];
  }

  const f32x4 fz = {0.f, 0.f, 0.f, 0.f};
  f32x4 Ov[4] = {fz, fz, fz, fz};
  float l_run = 0.f;

  for (int jt = jt_lo; jt <= jt_hi; ++jt) {
    int j0 = jt << 6;
    __syncthreads();
    // prefetch next tile
    int jn = (jt < jt_hi) ? ((jt + 1) << 6) : j0;
    int jcn = jn + srow; if (jcn > S_ - 1) jcn = S_ - 1;
    const int4* kp = (const int4*)(kb_base + (size_t)jcn * E_);
    int4 nk0 = kp[0], nk1 = kp[1];
    const int4* vp = (const int4*)(vb_base + jn);
    int4 nv0 = vp[0], nv1 = vp[1];
    // commit current
    *(int4*)&Ks[srow][scol]     = ka0; *(int4*)&Ks[srow][scol + 8] = ka1;
    *(int4*)&Vt[srow][scol]     = va0; *(int4*)&Vt[srow][scol + 8] = va1;
    __syncthreads();

    // S^T = K . Q^T : lane holds one q-row (i=l15), 16 j's
    f32x4 st[4];
#pragma unroll
    for (int nt = 0; nt < 4; ++nt) {
      bf16x8 kf0 = *(const bf16x8*)&Ks[nt * 16 + l15][quad * 8];
      bf16x8 kf1 = *(const bf16x8*)&Ks[nt * 16 + l15][32 + quad * 8];
      f32x4 s = MFMA16(kf0, qf0, fz);
      st[nt] = MFMA16(kf1, qf1, s);
    }

    bool full = ((j0 + 63 - i0) <= WIN_) && ((i0 + 63 - j0) <= WIN_)
                && (j0 + 63 < S_) && (i0 + 63 < S_);
    float ps = 0.f;
    float jq = (float)(j0 + quad * 4);
    if (full) {
#pragma unroll
      for (int nt = 0; nt < 4; ++nt) {
        f32x4 g4 = *(const f32x4*)&gbs[(j0 - jbase) + nt * 16 + quad * 4];
#pragma unroll
        for (int r = 0; r < 4; ++r) {
          float f = fdi - (jq + (float)(nt * 16 + r));
          float gate = __builtin_amdgcn_rcpf(fmaf(av, g4[r], 1.f));
          float p = __expf(fmaf(f * f, coef, st[nt][r]) * gate);
          st[nt][r] = p; ps += p;
        }
      }
    } else {
#pragma unroll
      for (int nt = 0; nt < 4; ++nt) {
        f32x4 g4 = *(const f32x4*)&gbs[(j0 - jbase) + nt * 16 + quad * 4];
#pragma unroll
        for (int r = 0; r < 4; ++r) {
          int j = j0 + nt * 16 + quad * 4 + r;
          float fj = (j < S_) ? (float)j : 1e5f;
          float f = fdi - fj;
          float gate = __builtin_amdgcn_rcpf(fmaf(av, g4[r], 1.f));
          float t = fmaf(f * f, coef, st[nt][r]) * gate;
          t = (__builtin_fabsf(f) <= 1024.f) ? t : -1e30f;
          float p = __expf(t);
          st[nt][r] = p; ps += p;
        }
      }
    }
    ps += __shfl_xor(ps, 16);
    ps += __shfl_xor(ps, 32);
    l_run += ps;

    // pack P (bf16) to per-wave LDS
#pragma unroll
    for (int nt = 0; nt < 4; ++nt) {
      uint2 pk;
      pk.x = (unsigned int)f2bf(st[nt][0]) | ((unsigned int)f2bf(st[nt][1]) << 16);
      pk.y = (unsigned int)f2bf(st[nt][2]) | ((unsigned int)f2bf(st[nt][3]) << 16);
      *(uint2*)&Ps[w][l15][nt * 16 + quad * 4] = pk;
    }
    // O += P @ V  (no rescale needed: fixed-reference softmax)
    bf16x8 p0 = *(const bf16x8*)&Ps[w][l15][quad * 8];
    bf16x8 p1 = *(const bf16x8*)&Ps[w][l15][32 + quad * 8];
#pragma unroll
    for (int nt = 0; nt < 4; ++nt) {
      bf16x8 v0 = *(const bf16x8*)&Vt[nt * 16 + l15][quad * 8];
      bf16x8 v1 = *(const bf16x8*)&Vt[nt * 16 + l15][32 + quad * 8];
      Ov[nt] = MFMA16(p0, v0, Ov[nt]);
      Ov[nt] = MFMA16(p1, v1, Ov[nt]);
    }
    ka0 = nk0; ka1 = nk1; va0 = nv0; va1 = nv1;
  }

  if (lane < 16) lls[w][lane] = 1.f / l_run;
  f32x4 inv4 = *(const f32x4*)&lls[w][quad * 4];
#pragma unroll
  for (int r = 0; r < 4; ++r) {
    int irow = i0 + w * 16 + quad * 4 + r;
    if (irow < S_) {
#pragma unroll
      for (int nt = 0; nt < 4; ++nt) {
        float o = Ov[nt][r] * inv4[r];
        ushort_t hv = f2bf(o);
        size_t idx = ((size_t)(b * S_ + irow)) * E_ + h * 64 + nt * 16 + l15;
        ahi[idx] = hv;
        alo[idx] = f2bf(o - bf2f(hv));
      }
    }
  }
}

// ---------------------------------------------------------------------------
// Output projection, 64x128 tile, 2x2 waves (32x64 each), 2-term split:
// C = (Ahi + Alo) @ Whi + bias (fp32 out)
// ---------------------------------------------------------------------------
__global__ __launch_bounds__(256) void gemm_out_kernel(
    const ushort_t* __restrict__ Ahi, const ushort_t* __restrict__ Alo,
    const ushort_t* __restrict__ Whi, const float* __restrict__ bias,
    float* __restrict__ C)
{
  __shared__ __align__(16) ushort_t AsH[64][40];
  __shared__ __align__(16) ushort_t AsL[64][40];
  __shared__ __align__(16) ushort_t BsW[128][40];
  int tid = threadIdx.x;
  int lane = tid & 63, w = tid >> 6;
  int l15 = lane & 15, quad = lane >> 4;
  int wm = (w & 1) * 32, wn = (w >> 1) * 64;
  int bm = blockIdx.x * 64, bn = blockIdx.y * 128;

  int ar = tid >> 2, ac = (tid & 3) * 8;
  int am = bm + ar; if (am >= MROWS) am = MROWS - 1;
  const ushort_t* ahp = Ahi + (size_t)am * E_ + ac;
  const ushort_t* alp = Alo + (size_t)am * E_ + ac;
  int br = tid >> 1, bc = (tid & 1) * 16;
  const ushort_t* bp = Whi + (size_t)(bn + br) * E_ + bc;

  const f32x4 fz = {0.f, 0.f, 0.f, 0.f};
  f32x4 acc[2][4];
#pragma unroll
  for (int mt = 0; mt < 2; ++mt)
#pragma unroll
    for (int nt = 0; nt < 4; ++nt) acc[mt][nt] = fz;

  int4 ph = *(const int4*)ahp, pl = *(const int4*)alp;
  int4 pb0 = *(const int4*)bp, pb1 = *(const int4*)(bp + 8);

  for (int k0 = 0; k0 < E_; k0 += 32) {
    __syncthreads();
    int kn = (k0 + 32 < E_) ? (k0 + 32) : k0;
    int4 nh = *(const int4*)(ahp + kn), nl = *(const int4*)(alp + kn);
    int4 nb0 = *(const int4*)(bp + kn), nb1 = *(const int4*)(bp + kn + 8);
    *(int4*)&AsH[ar][ac] = ph;
    *(int4*)&AsL[ar][ac] = pl;
    *(int4*)&BsW[br][bc] = pb0; *(int4*)&BsW[br][bc + 8] = pb1;
    __syncthreads();
    bf16x8 ah[2], al[2], bw[4];
#pragma unroll
    for (int mt = 0; mt < 2; ++mt) {
      ah[mt] = *(const bf16x8*)&AsH[wm + mt * 16 + l15][quad * 8];
      al[mt] = *(const bf16x8*)&AsL[wm + mt * 16 + l15][quad * 8];
    }
#pragma unroll
    for (int nt = 0; nt < 4; ++nt) bw[nt] = *(const bf16x8*)&BsW[wn + nt * 16 + l15][quad * 8];
#pragma unroll
    for (int mt = 0; mt < 2; ++mt)
#pragma unroll
      for (int nt = 0; nt < 4; ++nt) {
        acc[mt][nt] = MFMA16(ah[mt], bw[nt], acc[mt][nt]);
        acc[mt][nt] = MFMA16(al[mt], bw[nt], acc[mt][nt]);
      }
    ph = nh; pl = nl; pb0 = nb0; pb1 = nb1;
  }
#pragma unroll
  for (int nt = 0; nt < 4; ++nt) {
    float bb = bias[bn + wn + nt * 16 + l15];
#pragma unroll
    for (int mt = 0; mt < 2; ++mt)
#pragma unroll
      for (int r = 0; r < 4; ++r) {
        int m = bm + wm + mt * 16 + quad * 4 + r;
        if (m < MROWS)
          C[(size_t)m * E_ + bn + wn + nt * 16 + l15] = acc[mt][nt][r] + bb;
      }
  }
}

// ---------------------------------------------------------------------------
extern "C" void kernel_launch(void* const* d_in, const int* in_sizes, int n_in,
                              void* d_out, int out_size, void* d_ws, size_t ws_size,
                              hipStream_t stream) {
  const float* x  = (const float*)d_in[0];
  const float* Wq = (const float*)d_in[1];
  const float* bq = (const float*)d_in[2];
  const float* Wk = (const float*)d_in[3];
  const float* bk = (const float*)d_in[4];
  const float* Wv = (const float*)d_in[5];
  const float* bv = (const float*)d_in[6];
  const float* Wo = (const float*)d_in[7];
  const float* bo = (const float*)d_in[8];
  const float* wg = (const float*)d_in[9];
  const float* bg = (const float*)d_in[10];

  char* p = (char*)d_ws;
  ushort_t* xb     = (ushort_t*)p; p += (size_t)MROWS * E_ * 2;          // 4.20 MB
  ushort_t* Wt_all = (ushort_t*)p; p += (size_t)3 * E_ * E_ * 2;         // 1.57 MB
  ushort_t* WoHi   = (ushort_t*)p; p += (size_t)E_ * E_ * 2;             // 0.52 MB
  ushort_t* qkb    = (ushort_t*)p; p += (size_t)2 * MROWS * E_ * 2;      // 8.39 MB
  ushort_t* vT     = (ushort_t*)p; p += (size_t)B_ * H_ * 64 * SP_ * 2;  // 4.46 MB
  float*    gq_acc = (float*)p;    p += (size_t)GBUFN * 4;
  float*    gk_acc = (float*)p;    p += (size_t)GBUFN * 4;
  ushort_t* aHi    = (ushort_t*)p; p += (size_t)MROWS * E_ * 2;
  ushort_t* aLo    = (ushort_t*)p; p += (size_t)MROWS * E_ * 2;          // ~28 MB

  hipMemsetAsync(gq_acc, 0, 2 * (size_t)GBUFN * 4, stream);
  hipLaunchKernelGGL(convert_all_kernel, dim3(3073), dim3(256), 0, stream,
                     x, Wq, Wk, Wv, Wo, xb, Wt_all, WoHi);
  hipLaunchKernelGGL(gemm_qkv_kernel, dim3(33, 4, 3), dim3(256), 0, stream,
                     xb, Wt_all, bq, bk, bv, wg, qkb, vT, gq_acc, gk_acc);
  hipLaunchKernelGGL(attn_kernel, dim3(33 * 16), dim3(256), 0, stream,
                     qkb, qkb + (size_t)MROWS * E_, vT, gq_acc, gk_acc, bg, aHi, aLo);
  hipLaunchKernelGGL(gemm_out_kernel, dim3(65, 4), dim3(256), 0, stream,
                     aHi, aLo, WoHi, bo, (float*)d_out);
}

// Round 6
// 175.565 us; speedup vs baseline: 3.5721x; 1.0118x over previous
//
#include <hip/hip_runtime.h>
#include <cstdint>
#include <cstddef>

#define B_ 2
#define S_ 2049
#define E_ 512
#define H_ 8
#define WIN_ 1024
#define MROWS (B_*S_)     // 4098
#define SP_ 2176          // padded seq for vT rows
#define GBUFN 4104
#define HS_ (H_*S_)       // 16392
#define BHS_ (B_*H_*S_)   // 32784

typedef unsigned short ushort_t;
typedef __attribute__((ext_vector_type(8))) short bf16x8;   // 8 bf16 (4 VGPRs)
typedef __attribute__((ext_vector_type(4))) float f32x4;

#define MFMA16(a,b,c) __builtin_amdgcn_mfma_f32_16x16x32_bf16(a,b,c,0,0,0)

__device__ __forceinline__ ushort_t f2bf(float f) {          // RNE fp32->bf16
  unsigned int u = __float_as_uint(f);
  u += 0x7fffu + ((u >> 16) & 1u);
  return (ushort_t)(u >> 16);
}
__device__ __forceinline__ float bf2f(ushort_t h) {
  return __uint_as_float(((unsigned int)h) << 16);
}

// ---------------------------------------------------------------------------
// W [k][n] fp32 -> Wt [n][k] bf16 (z<3: Wq/Wk/Wv; z==3: Wo -> WoHi)
// ---------------------------------------------------------------------------
__global__ __launch_bounds__(256) void convert_w_kernel(
    const float* __restrict__ W0, const float* __restrict__ W1,
    const float* __restrict__ W2, const float* __restrict__ W3,
    ushort_t* __restrict__ Wt_all, ushort_t* __restrict__ WoHi)
{
  __shared__ float tile[32][33];
  int z = blockIdx.z;
  const float* W = (z == 0) ? W0 : (z == 1) ? W1 : (z == 2) ? W2 : W3;
  int k0 = blockIdx.x * 32, n0 = blockIdx.y * 32;
  int r = threadIdx.x >> 5, c = threadIdx.x & 31;
#pragma unroll
  for (int i = 0; i < 4; ++i) {
    int rr = r + i * 8;
    tile[rr][c] = W[(size_t)(k0 + rr) * E_ + n0 + c];
  }
  __syncthreads();
#pragma unroll
  for (int i = 0; i < 4; ++i) {
    int rr = r + i * 8;
    float v = tile[c][rr];                       // = W[k0+c][n0+rr]
    size_t dst = (size_t)(n0 + rr) * E_ + k0 + c;
    if (z < 3) Wt_all[(size_t)z * E_ * E_ + dst] = f2bf(v);
    else       WoHi[dst] = f2bf(v);
  }
}

// ---------------------------------------------------------------------------
// QKV projection, 64x128 tile, 2x2 waves (32x64 each), BK=32, reg-prefetch.
// Reads x fp32 directly (in-register convert). z<2: row-major bf16 + fused
// gate partial dots. z==2: transposed store to vT[b][h][d][s]. Grid 780.
// ---------------------------------------------------------------------------
__global__ __launch_bounds__(256) void gemm_qkv_kernel(
    const float* __restrict__ x, const ushort_t* __restrict__ Wt_all,
    const float* __restrict__ bq, const float* __restrict__ bk,
    const float* __restrict__ bv, const float* __restrict__ wg,
    ushort_t* __restrict__ qkb, ushort_t* __restrict__ vT,
    float* __restrict__ gq_acc, float* __restrict__ gk_acc)
{
  __shared__ __align__(16) ushort_t As[64][40];
  __shared__ __align__(16) ushort_t Bs[128][40];
  int tid = threadIdx.x;
  int lane = tid & 63, w = tid >> 6;
  int l15 = lane & 15, quad = lane >> 4;
  int wm = (w & 1) * 32, wn = (w >> 1) * 64;
  int z = blockIdx.z;
  const ushort_t* Wt = Wt_all + (size_t)z * E_ * E_;
  const float* bias = (z == 0) ? bq : (z == 1) ? bk : bv;
  int bm = blockIdx.x * 64, bn = blockIdx.y * 128;

  int ar = tid >> 2, acq = (tid & 3) * 8;
  int am = bm + ar; if (am >= MROWS) am = MROWS - 1;
  const float* ap = x + (size_t)am * E_ + acq;
  int br = tid >> 1, bcq = (tid & 1) * 16;
  const ushort_t* bp = Wt + (size_t)(bn + br) * E_ + bcq;

  const f32x4 fz = {0.f, 0.f, 0.f, 0.f};
  f32x4 acc[2][4];
#pragma unroll
  for (int mt = 0; mt < 2; ++mt)
#pragma unroll
    for (int nt = 0; nt < 4; ++nt) acc[mt][nt] = fz;

  float4 pa0 = *(const float4*)ap, pa1 = *(const float4*)(ap + 4);
  int4  pb0 = *(const int4*)bp,   pb1 = *(const int4*)(bp + 8);

  for (int k0 = 0; k0 < E_; k0 += 32) {
    __syncthreads();
    int kn = (k0 + 32 < E_) ? (k0 + 32) : k0;
    float4 na0 = *(const float4*)(ap + kn), na1 = *(const float4*)(ap + kn + 4);
    int4  nb0 = *(const int4*)(bp + kn),   nb1 = *(const int4*)(bp + kn + 8);
    union { int4 v; ushort_t u[8]; } cv;
    cv.u[0] = f2bf(pa0.x); cv.u[1] = f2bf(pa0.y); cv.u[2] = f2bf(pa0.z); cv.u[3] = f2bf(pa0.w);
    cv.u[4] = f2bf(pa1.x); cv.u[5] = f2bf(pa1.y); cv.u[6] = f2bf(pa1.z); cv.u[7] = f2bf(pa1.w);
    *(int4*)&As[ar][acq] = cv.v;
    *(int4*)&Bs[br][bcq] = pb0; *(int4*)&Bs[br][bcq + 8] = pb1;
    __syncthreads();
    bf16x8 a[2], bfr[4];
#pragma unroll
    for (int mt = 0; mt < 2; ++mt) a[mt] = *(const bf16x8*)&As[wm + mt * 16 + l15][quad * 8];
#pragma unroll
    for (int nt = 0; nt < 4; ++nt) bfr[nt] = *(const bf16x8*)&Bs[wn + nt * 16 + l15][quad * 8];
#pragma unroll
    for (int mt = 0; mt < 2; ++mt)
#pragma unroll
      for (int nt = 0; nt < 4; ++nt)
        acc[mt][nt] = MFMA16(a[mt], bfr[nt], acc[mt][nt]);
    pa0 = na0; pa1 = na1; pb0 = nb0; pb1 = nb1;
  }

  float bb[4];
#pragma unroll
  for (int nt = 0; nt < 4; ++nt) bb[nt] = bias[bn + wn + nt * 16 + l15];

  if (z < 2) {
    ushort_t* C = qkb + (size_t)z * MROWS * E_;
#pragma unroll
    for (int mt = 0; mt < 2; ++mt)
#pragma unroll
      for (int nt = 0; nt < 4; ++nt)
#pragma unroll
        for (int r = 0; r < 4; ++r) {
          int m = bm + wm + mt * 16 + quad * 4 + r;
          if (m < MROWS)
            C[(size_t)m * E_ + bn + wn + nt * 16 + l15] = f2bf(acc[mt][nt][r] + bb[nt]);
        }
    const float* wgp = wg + (size_t)z * E_;
    float wv[4];
#pragma unroll
    for (int nt = 0; nt < 4; ++nt) wv[nt] = wgp[bn + wn + nt * 16 + l15];
    float* gacc = (z == 0) ? gq_acc : gk_acc;
#pragma unroll
    for (int mt = 0; mt < 2; ++mt)
#pragma unroll
      for (int r = 0; r < 4; ++r) {
        float s = 0.f;
#pragma unroll
        for (int nt = 0; nt < 4; ++nt) s = fmaf(acc[mt][nt][r] + bb[nt], wv[nt], s);
        s += __shfl_xor(s, 1, 16); s += __shfl_xor(s, 2, 16);
        s += __shfl_xor(s, 4, 16); s += __shfl_xor(s, 8, 16);
        int m = bm + wm + mt * 16 + quad * 4 + r;
        if (l15 == 0 && m < MROWS) atomicAdd(&gacc[m], s);
      }
  } else {
#pragma unroll
    for (int mt = 0; mt < 2; ++mt)
#pragma unroll
      for (int nt = 0; nt < 4; ++nt) {
        int dg = bn + wn + nt * 16 + l15;
        int h = dg >> 6, d = dg & 63;
#pragma unroll
        for (int r = 0; r < 4; ++r) {
          int m = bm + wm + mt * 16 + quad * 4 + r;
          if (m < MROWS) {
            int b = (m >= S_) ? 1 : 0;
            int i = m - b * S_;
            vT[((size_t)(b * H_ + h) * 64 + d) * SP_ + i] = f2bf(acc[mt][nt][r] + bb[nt]);
          }
        }
      }
  }
}

// ---------------------------------------------------------------------------
// MFMA flash attention, S^T form, fixed-reference softmax (no max tracking),
// j-window SPLIT IN TWO per (qt,h,b): partials are linear (O=O1+O2, l=l1+l2).
// Block = 64 q-rows x (h,b) x half; 4 waves x 16 rows; 64-col j-tiles.
// Stores unnormalized fp32 O-partial + l-partial. Grid 1056.
// ---------------------------------------------------------------------------
__global__ __launch_bounds__(256) void attn_kernel(
    const ushort_t* __restrict__ qb, const ushort_t* __restrict__ kb,
    const ushort_t* __restrict__ vT, const float* __restrict__ gq_raw,
    const float* __restrict__ gk_raw, const float* __restrict__ bgate,
    float* __restrict__ Opart, float* __restrict__ Lpart)
{
  __shared__ __align__(16) ushort_t Ks[64][72];    // [j][d]
  __shared__ __align__(16) ushort_t Vt[64][72];    // [d][j]
  __shared__ __align__(16) ushort_t Ps[4][16][72]; // per-wave P [i][j]
  __shared__ float gbs[1088];

  int tid = threadIdx.x;
  int lane = tid & 63, w = tid >> 6;
  int l15 = lane & 15, quad = lane >> 4;

  // middle-out q-tile order; 32 blocks (16 bh x 2 halves) per qt
  int sub = blockIdx.x & 31;
  int qidx = blockIdx.x >> 5;
  int off = (qidx + 1) >> 1;
  int qt = 16 + ((qidx & 1) ? -off : off);          // 0..32
  int bh = sub & 15, half = sub >> 4;
  int h = bh & 7, b = bh >> 3;
  int i0 = qt * 64;
  const float coef = -0.5f / (512.f * 512.f);       // sigma = WIN/2

  // per-thread q-row
  int i = i0 + w * 16 + l15;
  int ic = (i < S_) ? i : S_ - 1;
  bf16x8 qf0 = *(const bf16x8*)&qb[((size_t)(b * S_ + ic)) * E_ + h * 64 + quad * 8];
  bf16x8 qf1 = *(const bf16x8*)&qb[((size_t)(b * S_ + ic)) * E_ + h * 64 + 32 + quad * 8];
#pragma unroll
  for (int e = 0; e < 8; ++e) {                     // pre-scale by D^-0.5 (exact)
    qf0[e] = (short)f2bf(bf2f((ushort_t)qf0[e]) * 0.125f);
    qf1[e] = (short)f2bf(bf2f((ushort_t)qf1[e]) * 0.125f);
  }
  float av = __expf(-(gq_raw[b * S_ + ic] + bgate[0]));
  float fdi = (i < S_) ? (float)i : -1e5f;

  int jlo = i0 - WIN_; if (jlo < 0) jlo = 0;
  int jt_lo = jlo >> 6;
  int jhi = i0 + 63 + WIN_; if (jhi > S_ - 1) jhi = S_ - 1;
  int jt_hi = jhi >> 6;
  int L = jt_hi - jt_lo + 1;                        // >= 17 always
  int Lh = (L + 1) >> 1;
  int myLo = half ? (jt_lo + Lh) : jt_lo;
  int myHi = half ? jt_hi : (jt_lo + Lh - 1);
  int jbase = myLo << 6;
  int nwin = (myHi - myLo + 1) << 6;                // <= 1088

  for (int tt = tid; tt < nwin; tt += 256) {
    int j = jbase + tt; int jc = (j < S_) ? j : S_ - 1;
    gbs[tt] = __expf(-gk_raw[b * S_ + jc]);
  }

  // staging maps: K rows=j, V^T rows=d; both 64x64, 2 int4 per thread
  int srow = tid >> 2, scol = (tid & 3) * 16;
  const ushort_t* kb_base = kb + (size_t)b * S_ * E_ + h * 64 + scol;
  const ushort_t* vb_base = vT + ((size_t)(b * H_ + h) * 64 + srow) * SP_ + scol;

  int4 ka0, ka1, va0, va1;
  {
    int jc0 = jbase + srow; if (jc0 > S_ - 1) jc0 = S_ - 1;
    const int4* kp = (const int4*)(kb_base + (size_t)jc0 * E_);
    ka0 = kp[0]; ka1 = kp[1];
    const int4* vp = (const int4*)(vb_base + jbase);
    va0 = vp[0]; va1 = vp[1];
  }

  const f32x4 fz = {0.f, 0.f, 0.f, 0.f};
  f32x4 Ov[4] = {fz, fz, fz, fz};
  float l_run = 0.f;

  for (int jt = myLo; jt <= myHi; ++jt) {
    int j0 = jt << 6;
    __syncthreads();
    int jn = (jt < myHi) ? ((jt + 1) << 6) : j0;
    int jcn = jn + srow; if (jcn > S_ - 1) jcn = S_ - 1;
    const int4* kp = (const int4*)(kb_base + (size_t)jcn * E_);
    int4 nk0 = kp[0], nk1 = kp[1];
    const int4* vp = (const int4*)(vb_base + jn);
    int4 nv0 = vp[0], nv1 = vp[1];
    *(int4*)&Ks[srow][scol] = ka0; *(int4*)&Ks[srow][scol + 8] = ka1;
    *(int4*)&Vt[srow][scol] = va0; *(int4*)&Vt[srow][scol + 8] = va1;
    __syncthreads();

    // S^T = K . Q^T : lane holds one q-row (i=l15), 16 j's
    f32x4 st[4];
#pragma unroll
    for (int nt = 0; nt < 4; ++nt) {
      bf16x8 kf0 = *(const bf16x8*)&Ks[nt * 16 + l15][quad * 8];
      bf16x8 kf1 = *(const bf16x8*)&Ks[nt * 16 + l15][32 + quad * 8];
      f32x4 s = MFMA16(kf0, qf0, fz);
      st[nt] = MFMA16(kf1, qf1, s);
    }

    bool full = ((j0 + 63 - i0) <= WIN_) && ((i0 + 63 - j0) <= WIN_)
                && (j0 + 63 < S_) && (i0 + 63 < S_);
    float ps = 0.f;
    float jq = (float)(j0 + quad * 4);
    if (full) {
#pragma unroll
      for (int nt = 0; nt < 4; ++nt) {
        f32x4 g4 = *(const f32x4*)&gbs[(j0 - jbase) + nt * 16 + quad * 4];
#pragma unroll
        for (int r = 0; r < 4; ++r) {
          float f = fdi - (jq + (float)(nt * 16 + r));
          float gate = __builtin_amdgcn_rcpf(fmaf(av, g4[r], 1.f));
          float p = __expf(fmaf(f * f, coef, st[nt][r]) * gate);
          st[nt][r] = p; ps += p;
        }
      }
    } else {
#pragma unroll
      for (int nt = 0; nt < 4; ++nt) {
        f32x4 g4 = *(const f32x4*)&gbs[(j0 - jbase) + nt * 16 + quad * 4];
#pragma unroll
        for (int r = 0; r < 4; ++r) {
          int j = j0 + nt * 16 + quad * 4 + r;
          float fj = (j < S_) ? (float)j : 1e5f;
          float f = fdi - fj;
          float gate = __builtin_amdgcn_rcpf(fmaf(av, g4[r], 1.f));
          float t = fmaf(f * f, coef, st[nt][r]) * gate;
          t = (__builtin_fabsf(f) <= 1024.f) ? t : -1e30f;
          float p = __expf(t);
          st[nt][r] = p; ps += p;
        }
      }
    }
    ps += __shfl_xor(ps, 16);
    ps += __shfl_xor(ps, 32);
    l_run += ps;

#pragma unroll
    for (int nt = 0; nt < 4; ++nt) {
      uint2 pk;
      pk.x = (unsigned int)f2bf(st[nt][0]) | ((unsigned int)f2bf(st[nt][1]) << 16);
      pk.y = (unsigned int)f2bf(st[nt][2]) | ((unsigned int)f2bf(st[nt][3]) << 16);
      *(uint2*)&Ps[w][l15][nt * 16 + quad * 4] = pk;
    }
    bf16x8 p0 = *(const bf16x8*)&Ps[w][l15][quad * 8];
    bf16x8 p1 = *(const bf16x8*)&Ps[w][l15][32 + quad * 8];
#pragma unroll
    for (int nt = 0; nt < 4; ++nt) {
      bf16x8 v0 = *(const bf16x8*)&Vt[nt * 16 + l15][quad * 8];
      bf16x8 v1 = *(const bf16x8*)&Vt[nt * 16 + l15][32 + quad * 8];
      Ov[nt] = MFMA16(p0, v0, Ov[nt]);
      Ov[nt] = MFMA16(p1, v1, Ov[nt]);
    }
    ka0 = nk0; ka1 = nk1; va0 = nv0; va1 = nv1;
  }

  // store unnormalized partials
  if (lane < 16) {
    int irow = i0 + w * 16 + lane;
    if (irow < S_)
      Lpart[(size_t)half * BHS_ + (size_t)(b * H_ + h) * S_ + irow] = l_run;
  }
#pragma unroll
  for (int r = 0; r < 4; ++r) {
    int irow = i0 + w * 16 + quad * 4 + r;
    if (irow < S_) {
      size_t base = ((size_t)half * BHS_ + (size_t)(b * H_ + h) * S_ + irow) * (size_t)64;
#pragma unroll
      for (int nt = 0; nt < 4; ++nt)
        Opart[base + nt * 16 + l15] = Ov[nt][r];
    }
  }
}

// ---------------------------------------------------------------------------
// Combine halves: o = (O1+O2)/(l1+l2); emit hi/lo bf16 split, row-major.
// 16 threads per (b,h,i) row; 16 rows per block; grid 2049.
// ---------------------------------------------------------------------------
__global__ __launch_bounds__(256) void combine_kernel(
    const float* __restrict__ Opart, const float* __restrict__ Lpart,
    ushort_t* __restrict__ ahi, ushort_t* __restrict__ alo)
{
  int tid = threadIdx.x;
  int gi = blockIdx.x * 16 + (tid >> 4);            // [0, 32784)
  int d4 = tid & 15;
  int b = gi / HS_;
  int rem = gi - b * HS_;
  int h = rem / S_;
  int i = rem - h * S_;
  size_t p0 = (size_t)(b * H_ + h) * S_ + i;
  size_t p1 = p0 + (size_t)BHS_;
  float inv = __builtin_amdgcn_rcpf(Lpart[p0] + Lpart[p1]);
  float4 o1 = *(const float4*)&Opart[p0 * 64 + d4 * 4];
  float4 o2 = *(const float4*)&Opart[p1 * 64 + d4 * 4];
  float o[4] = {(o1.x + o2.x) * inv, (o1.y + o2.y) * inv,
                (o1.z + o2.z) * inv, (o1.w + o2.w) * inv};
  ushort4 hi, lo;
  hi.x = f2bf(o[0]); lo.x = f2bf(o[0] - bf2f(hi.x));
  hi.y = f2bf(o[1]); lo.y = f2bf(o[1] - bf2f(hi.y));
  hi.z = f2bf(o[2]); lo.z = f2bf(o[2] - bf2f(hi.z));
  hi.w = f2bf(o[3]); lo.w = f2bf(o[3] - bf2f(hi.w));
  size_t oidx = ((size_t)b * S_ + i) * E_ + h * 64 + d4 * 4;
  *(ushort4*)&ahi[oidx] = hi;
  *(ushort4*)&alo[oidx] = lo;
}

// ---------------------------------------------------------------------------
// Output projection, 64x64 tile, 4 waves x (16m x 64n), 2-term split:
// C = (Ahi + Alo) @ Whi + bias (fp32 out). Grid 520.
// ---------------------------------------------------------------------------
__global__ __launch_bounds__(256) void gemm_out_kernel(
    const ushort_t* __restrict__ Ahi, const ushort_t* __restrict__ Alo,
    const ushort_t* __restrict__ Whi, const float* __restrict__ bias,
    float* __restrict__ C)
{
  __shared__ __align__(16) ushort_t AsH[64][40];
  __shared__ __align__(16) ushort_t AsL[64][40];
  __shared__ __align__(16) ushort_t BsW[64][40];
  int tid = threadIdx.x;
  int lane = tid & 63, w = tid >> 6;
  int l15 = lane & 15, quad = lane >> 4;
  int bm = blockIdx.x * 64, bn = blockIdx.y * 64;
  int sr = tid >> 2, sc = (tid & 3) * 8;
  int am = bm + sr; if (am >= MROWS) am = MROWS - 1;
  const ushort_t* ahp = Ahi + (size_t)am * E_ + sc;
  const ushort_t* alp = Alo + (size_t)am * E_ + sc;
  const ushort_t* bp  = Whi + (size_t)(bn + sr) * E_ + sc;

  const f32x4 fz = {0.f, 0.f, 0.f, 0.f};
  f32x4 acc[4] = {fz, fz, fz, fz};

  int4 ph = *(const int4*)ahp, pl = *(const int4*)alp, pb = *(const int4*)bp;

  for (int k0 = 0; k0 < E_; k0 += 32) {
    __syncthreads();
    int kn = (k0 + 32 < E_) ? (k0 + 32) : k0;
    int4 nh = *(const int4*)(ahp + kn);
    int4 nl = *(const int4*)(alp + kn);
    int4 nb = *(const int4*)(bp + kn);
    *(int4*)&AsH[sr][sc] = ph;
    *(int4*)&AsL[sr][sc] = pl;
    *(int4*)&BsW[sr][sc] = pb;
    __syncthreads();
    bf16x8 ah = *(const bf16x8*)&AsH[w * 16 + l15][quad * 8];
    bf16x8 al = *(const bf16x8*)&AsL[w * 16 + l15][quad * 8];
#pragma unroll
    for (int nt = 0; nt < 4; ++nt) {
      bf16x8 bw = *(const bf16x8*)&BsW[nt * 16 + l15][quad * 8];
      acc[nt] = MFMA16(ah, bw, acc[nt]);
      acc[nt] = MFMA16(al, bw, acc[nt]);
    }
    ph = nh; pl = nl; pb = nb;
  }
#pragma unroll
  for (int nt = 0; nt < 4; ++nt) {
    float bb = bias[bn + nt * 16 + l15];
#pragma unroll
    for (int r = 0; r < 4; ++r) {
      int m = bm + w * 16 + quad * 4 + r;
      if (m < MROWS)
        C[(size_t)m * E_ + bn + nt * 16 + l15] = acc[nt][r] + bb;
    }
  }
}

// ---------------------------------------------------------------------------
extern "C" void kernel_launch(void* const* d_in, const int* in_sizes, int n_in,
                              void* d_out, int out_size, void* d_ws, size_t ws_size,
                              hipStream_t stream) {
  const float* x  = (const float*)d_in[0];
  const float* Wq = (const float*)d_in[1];
  const float* bq = (const float*)d_in[2];
  const float* Wk = (const float*)d_in[3];
  const float* bk = (const float*)d_in[4];
  const float* Wv = (const float*)d_in[5];
  const float* bv = (const float*)d_in[6];
  const float* Wo = (const float*)d_in[7];
  const float* bo = (const float*)d_in[8];
  const float* wg = (const float*)d_in[9];
  const float* bg = (const float*)d_in[10];

  char* p = (char*)d_ws;
  ushort_t* Wt_all = (ushort_t*)p; p += (size_t)3 * E_ * E_ * 2;         // 1.57 MB
  ushort_t* WoHi   = (ushort_t*)p; p += (size_t)E_ * E_ * 2;             // 0.52 MB
  ushort_t* qkb    = (ushort_t*)p; p += (size_t)2 * MROWS * E_ * 2;      // 8.39 MB
  ushort_t* vT     = (ushort_t*)p; p += (size_t)B_ * H_ * 64 * SP_ * 2;  // 4.46 MB
  float*    gq_acc = (float*)p;    p += (size_t)GBUFN * 4;
  float*    gk_acc = (float*)p;    p += (size_t)GBUFN * 4;
  float*    Opart  = (float*)p;    p += (size_t)2 * BHS_ * 64 * 4;       // 16.8 MB
  float*    Lpart  = (float*)p;    p += (size_t)2 * BHS_ * 4;            // 0.26 MB
  ushort_t* aHi    = (ushort_t*)p; p += (size_t)MROWS * E_ * 2;
  ushort_t* aLo    = (ushort_t*)p; p += (size_t)MROWS * E_ * 2;          // ~40.5 MB

  hipMemsetAsync(gq_acc, 0, 2 * (size_t)GBUFN * 4, stream);
  hipLaunchKernelGGL(convert_w_kernel, dim3(16, 16, 4), dim3(256), 0, stream,
                     Wq, Wk, Wv, Wo, Wt_all, WoHi);
  hipLaunchKernelGGL(gemm_qkv_kernel, dim3(65, 4, 3), dim3(256), 0, stream,
                     x, Wt_all, bq, bk, bv, wg, qkb, vT, gq_acc, gk_acc);
  hipLaunchKernelGGL(attn_kernel, dim3(33 * 32), dim3(256), 0, stream,
                     qkb, qkb + (size_t)MROWS * E_, vT, gq_acc, gk_acc, bg,
                     Opart, Lpart);
  hipLaunchKernelGGL(combine_kernel, dim3(2049), dim3(256), 0, stream,
                     Opart, Lpart, aHi, aLo);
  hipLaunchKernelGGL(gemm_out_kernel, dim3(65, 8), dim3(256), 0, stream,
                     aHi, aLo, WoHi, bo, (float*)d_out);
}